// Round 1
// baseline (5745.720 us; speedup 1.0000x reference)
//
#include <hip/hip_runtime.h>
#include <math.h>

#define B_   128
#define N_   256
#define L_   64
#define NRR  (N_*N_)          // 65536
#define BRR  (B_*NRR)         // 8388608
#define BNL  (B_*N_*L_)       // 2097152

// ---------------------------------------------------------------------------
// A = diag(w1)*Sp + diag(w2)*Tp + w4.*Tp + w3.*T   (w1,w2 are diagonal mats)
// ---------------------------------------------------------------------------
__global__ __launch_bounds__(256) void k_build_A(
    const float* __restrict__ T, const float* __restrict__ Tp,
    const float* __restrict__ Sp, const float* __restrict__ w1,
    const float* __restrict__ w2, const float* __restrict__ w3,
    const float* __restrict__ w4, float* __restrict__ A) {
  int idx = blockIdx.x * 256 + threadIdx.x;
  if (idx >= BRR) return;
  int rc = idx & (NRR - 1);
  int r  = rc >> 8;
  float a = w1[r * N_ + r] * Sp[idx] + w2[r * N_ + r] * Tp[idx]
          + w4[rc] * Tp[idx] + w3[rc] * T[idx];
  A[idx] = a;
}

// ---------------------------------------------------------------------------
// G = A * A^T  (batched 256x256x256), 64x64 tile per block
// ---------------------------------------------------------------------------
__global__ __launch_bounds__(256) void k_aat(const float* __restrict__ A,
                                             float* __restrict__ G) {
  __shared__ float As[64][17];
  __shared__ float Bs[64][17];
  int b  = blockIdx.z;
  int it = blockIdx.x * 64, jt = blockIdx.y * 64;
  const float* Ab = A + (size_t)b * NRR;
  float acc[4][4] = {};
  int tid = threadIdx.x, tx = tid & 15, ty = tid >> 4;
  for (int k0 = 0; k0 < N_; k0 += 16) {
    for (int p = 0; p < 4; ++p) {
      int r = (tid >> 4) + p * 16;
      int kk = tid & 15;
      As[r][kk] = Ab[(it + r) * N_ + k0 + kk];
      Bs[r][kk] = Ab[(jt + r) * N_ + k0 + kk];
    }
    __syncthreads();
#pragma unroll
    for (int k = 0; k < 16; ++k) {
      float av[4], bv[4];
#pragma unroll
      for (int i = 0; i < 4; ++i) av[i] = As[ty * 4 + i][k];
#pragma unroll
      for (int j = 0; j < 4; ++j) bv[j] = Bs[tx * 4 + j][k];
#pragma unroll
      for (int i = 0; i < 4; ++i)
#pragma unroll
        for (int j = 0; j < 4; ++j) acc[i][j] += av[i] * bv[j];
    }
    __syncthreads();
  }
  float* Gb = G + (size_t)b * NRR;
  for (int i = 0; i < 4; ++i)
    for (int j = 0; j < 4; ++j)
      Gb[(it + ty * 4 + i) * N_ + jt + tx * 4 + j] = acc[i][j];
}

// ---------------------------------------------------------------------------
// Y = G * Q  (256x256 x 256x64), 64-row tile per block
// ---------------------------------------------------------------------------
__global__ __launch_bounds__(256) void k_gq(const float* __restrict__ G,
                                            const float* __restrict__ Q,
                                            float* __restrict__ Y) {
  __shared__ float Gs[64][17];
  __shared__ float Qs[16][65];
  int b  = blockIdx.y;
  int it = blockIdx.x * 64;
  const float* Gb = G + (size_t)b * NRR;
  const float* Qb = Q + (size_t)b * N_ * L_;
  float acc[4][4] = {};
  int tid = threadIdx.x, tx = tid & 15, ty = tid >> 4;
  for (int k0 = 0; k0 < N_; k0 += 16) {
    for (int p = 0; p < 4; ++p) {
      int r = (tid >> 4) + p * 16, kk = tid & 15;
      Gs[r][kk] = Gb[(it + r) * N_ + k0 + kk];
    }
    {
      int r = tid >> 6, cc = tid & 63;
      for (int p = 0; p < 4; ++p)
        Qs[r + p * 4][cc] = Qb[(k0 + r + p * 4) * L_ + cc];
    }
    __syncthreads();
#pragma unroll
    for (int k = 0; k < 16; ++k) {
      float gv[4], qv[4];
#pragma unroll
      for (int i = 0; i < 4; ++i) gv[i] = Gs[ty * 4 + i][k];
#pragma unroll
      for (int j = 0; j < 4; ++j) qv[j] = Qs[k][tx * 4 + j];
#pragma unroll
      for (int i = 0; i < 4; ++i)
#pragma unroll
        for (int j = 0; j < 4; ++j) acc[i][j] += gv[i] * qv[j];
    }
    __syncthreads();
  }
  float* Yb = Y + (size_t)b * N_ * L_;
  for (int i = 0; i < 4; ++i)
    for (int j = 0; j < 4; ++j)
      Yb[(it + ty * 4 + i) * L_ + tx * 4 + j] = acc[i][j];
}

// ---------------------------------------------------------------------------
// M = X^T * Y  (256x64 each -> 64x64), one block per batch
// ---------------------------------------------------------------------------
__global__ __launch_bounds__(256) void k_xty(const float* __restrict__ X,
                                             const float* __restrict__ Y,
                                             float* __restrict__ Mo) {
  __shared__ float Xs[64][65];
  __shared__ float Ys[64][65];
  int b = blockIdx.x;
  const float* Xb = X + (size_t)b * N_ * L_;
  const float* Yb = Y + (size_t)b * N_ * L_;
  int tid = threadIdx.x, tx = tid & 15, ty = tid >> 4;
  float acc[4][4] = {};
  for (int k0 = 0; k0 < N_; k0 += 64) {
    for (int p = 0; p < 16; ++p) {
      int r = (tid >> 6) + p * 4, cc = tid & 63;
      Xs[r][cc] = Xb[(k0 + r) * L_ + cc];
      Ys[r][cc] = Yb[(k0 + r) * L_ + cc];
    }
    __syncthreads();
#pragma unroll
    for (int k = 0; k < 64; ++k) {
      float xv[4], yv[4];
#pragma unroll
      for (int i = 0; i < 4; ++i) xv[i] = Xs[k][ty * 4 + i];
#pragma unroll
      for (int j = 0; j < 4; ++j) yv[j] = Ys[k][tx * 4 + j];
#pragma unroll
      for (int i = 0; i < 4; ++i)
#pragma unroll
        for (int j = 0; j < 4; ++j) acc[i][j] += xv[i] * yv[j];
    }
    __syncthreads();
  }
  float* Mb = Mo + (size_t)b * L_ * L_;
  for (int i = 0; i < 4; ++i)
    for (int j = 0; j < 4; ++j)
      Mb[(ty * 4 + i) * L_ + tx * 4 + j] = acc[i][j];
}

// ---------------------------------------------------------------------------
// deterministic pseudo-random init for Y0
// ---------------------------------------------------------------------------
__global__ __launch_bounds__(256) void k_init_Y(float* __restrict__ Y) {
  int idx = blockIdx.x * 256 + threadIdx.x;
  if (idx >= BNL) return;
  unsigned u = (unsigned)idx * 2654435761u;
  u ^= u >> 16; u *= 2246822519u; u ^= u >> 13; u *= 3266489917u; u ^= u >> 16;
  Y[idx] = (float)(int)u * 4.6566129e-10f;
}

// ---------------------------------------------------------------------------
// Cholesky of S (64x64 SPD) + inversion of lower factor. 64 threads/block.
// ---------------------------------------------------------------------------
__global__ __launch_bounds__(64) void k_cholinv(const float* __restrict__ Sg,
                                                float* __restrict__ Linvg) {
  __shared__ float a[64][65];
  __shared__ float li[64][65];
  int b = blockIdx.x, t = threadIdx.x;
  const float* Sb = Sg + (size_t)b * L_ * L_;
  for (int r = 0; r < 64; ++r) { a[r][t] = Sb[r * L_ + t]; li[r][t] = 0.f; }
  __syncthreads();
  for (int j = 0; j < 64; ++j) {
    if (t == j) a[j][j] = sqrtf(fmaxf(a[j][j], 1e-20f));
    __syncthreads();
    float dinv = 1.f / a[j][j];
    if (t > j) a[t][j] *= dinv;
    __syncthreads();
    if (t > j) {
      float lij = a[t][j];
      for (int k = j + 1; k <= t; ++k) a[t][k] -= lij * a[k][j];
    }
    __syncthreads();
  }
  // invert lower-triangular L: thread t computes column t
  {
    int c = t;
    li[c][c] = 1.f / a[c][c];
    for (int i = c + 1; i < 64; ++i) {
      float s = 0.f;
      for (int k = c; k < i; ++k) s += a[i][k] * li[k][c];
      li[i][c] = -s / a[i][i];
    }
  }
  __syncthreads();
  float* Lb = Linvg + (size_t)b * L_ * L_;
  for (int r = 0; r < 64; ++r) Lb[r * L_ + t] = li[r][t];
}

// ---------------------------------------------------------------------------
// Q = Y * Linv^T   (CholQR apply). One row of Y per thread.
// ---------------------------------------------------------------------------
__global__ __launch_bounds__(256) void k_yrinv(const float* __restrict__ Y,
                                               const float* __restrict__ Linv,
                                               float* __restrict__ Q) {
  __shared__ float Li[64][65];
  int b = blockIdx.x, t = threadIdx.x;
  const float* Lb = Linv + (size_t)b * L_ * L_;
  for (int p = 0; p < 16; ++p) {
    int r = (t >> 6) + p * 4, c = t & 63;
    Li[r][c] = Lb[r * L_ + c];
  }
  __syncthreads();
  const float* Yb = Y + (size_t)b * N_ * L_;
  float* Qb = Q + (size_t)b * N_ * L_;
  float yv[64];
#pragma unroll
  for (int k = 0; k < 64; ++k) yv[k] = Yb[t * L_ + k];
  for (int j = 0; j < 64; ++j) {
    float s = 0.f;
    for (int k = 0; k <= j; ++k) s += yv[k] * Li[j][k];
    Qb[t * L_ + j] = s;
  }
}

// ---------------------------------------------------------------------------
// parallel cyclic Jacobi eigendecomposition of 64x64 symmetric M; V out.
// ---------------------------------------------------------------------------
__global__ __launch_bounds__(256) void k_jacobi(float* __restrict__ Mg,
                                                float* __restrict__ Vg) {
  __shared__ float A[64][65];
  __shared__ float V[64][65];
  __shared__ float cs[32], sn[32];
  __shared__ int   pp[32], qq[32];
  int b = blockIdx.x, t = threadIdx.x;
  float* Mb = Mg + (size_t)b * L_ * L_;
  for (int p = 0; p < 16; ++p) {
    int r = (t >> 6) + p * 4, c = t & 63;
    A[r][c] = Mb[r * L_ + c];
    V[r][c] = (r == c) ? 1.f : 0.f;
  }
  __syncthreads();
  for (int sweep = 0; sweep < 8; ++sweep) {
    for (int rnd = 0; rnd < 63; ++rnd) {
      if (t < 32) {
        int p, q;
        if (t == 0) { p = 63; q = rnd; }
        else { p = (rnd + t) % 63; q = (rnd + 63 - t) % 63; }
        int i = min(p, q), j = max(p, q);
        float aii = A[i][i], ajj = A[j][j], aij = A[i][j];
        float c_ = 1.f, s_ = 0.f;
        if (fabsf(aij) > 1e-12f) {
          float tau = (ajj - aii) / (2.f * aij);
          float tt = (tau >= 0.f ? 1.f : -1.f) / (fabsf(tau) + sqrtf(1.f + tau * tau));
          c_ = rsqrtf(1.f + tt * tt);
          s_ = tt * c_;
        }
        pp[t] = i; qq[t] = j; cs[t] = c_; sn[t] = s_;
      }
      __syncthreads();
      for (int w = t; w < 2048; w += 256) {   // column rotations A <- A J
        int m = w >> 6, k = w & 63;
        int i = pp[m], j = qq[m]; float c_ = cs[m], s_ = sn[m];
        float x = A[k][i], y = A[k][j];
        A[k][i] = c_ * x - s_ * y;
        A[k][j] = s_ * x + c_ * y;
      }
      __syncthreads();
      for (int w = t; w < 2048; w += 256) {   // row rotations A <- J^T A
        int m = w >> 6, k = w & 63;
        int i = pp[m], j = qq[m]; float c_ = cs[m], s_ = sn[m];
        float x = A[i][k], y = A[j][k];
        A[i][k] = c_ * x - s_ * y;
        A[j][k] = s_ * x + c_ * y;
      }
      __syncthreads();
      for (int w = t; w < 2048; w += 256) {   // V <- V J
        int m = w >> 6, k = w & 63;
        int i = pp[m], j = qq[m]; float c_ = cs[m], s_ = sn[m];
        float x = V[k][i], y = V[k][j];
        V[k][i] = c_ * x - s_ * y;
        V[k][j] = s_ * x + c_ * y;
      }
      __syncthreads();
    }
  }
  for (int p = 0; p < 16; ++p) {
    int r = (t >> 6) + p * 4, c = t & 63;
    Mb[r * L_ + c] = A[r][c];
    Vg[(size_t)b * L_ * L_ + r * L_ + c] = V[r][c];
  }
}

// ---------------------------------------------------------------------------
// pick indices of K largest eigenvalues (diag of M)
// ---------------------------------------------------------------------------
__global__ void k_topk(const float* __restrict__ Mg, const int* __restrict__ Kp,
                       int* __restrict__ topidx) {
  int b = blockIdx.x;
  if (threadIdx.x != 0) return;
  const float* Mb = Mg + (size_t)b * L_ * L_;
  int K = *Kp; if (K > 16) K = 16;
  float vals[64]; bool used[64];
  for (int i = 0; i < 64; ++i) { vals[i] = Mb[i * L_ + i]; used[i] = false; }
  for (int j = 0; j < K; ++j) {
    int best = 0; float bv = -1e30f;
    for (int i = 0; i < 64; ++i)
      if (!used[i] && vals[i] > bv) { bv = vals[i]; best = i; }
    used[best] = true;
    topidx[b * 16 + j] = best;
  }
}

// ---------------------------------------------------------------------------
// U = Q * V[:, topidx]   (256x64 x 64xK)
// ---------------------------------------------------------------------------
__global__ __launch_bounds__(256) void k_formU(const float* __restrict__ Q,
                                               const float* __restrict__ V,
                                               const int* __restrict__ topidx,
                                               const int* __restrict__ Kp,
                                               float* __restrict__ U) {
  __shared__ float Vs[64][17];
  int b = blockIdx.x, t = threadIdx.x;
  int K = *Kp; if (K > 16) K = 16;
  if (t < 64) {
    for (int j = 0; j < 16; ++j)
      Vs[t][j] = (j < K) ? V[(size_t)b * L_ * L_ + t * L_ + topidx[b * 16 + j]] : 0.f;
  }
  __syncthreads();
  const float* Qb = Q + (size_t)b * N_ * L_;
  float qv[64];
#pragma unroll
  for (int k = 0; k < 64; ++k) qv[k] = Qb[t * L_ + k];
  float* Ub = U + (size_t)b * N_ * 16;
  for (int j = 0; j < 16; ++j) {
    float s = 0.f;
    if (j < K) {
#pragma unroll
      for (int k = 0; k < 64; ++k) s += qv[k] * Vs[k][j];
    }
    Ub[t * 16 + j] = s;
  }
}

// ---------------------------------------------------------------------------
// C = U^T * A   (Kx256 = sum over 256 rows)
// ---------------------------------------------------------------------------
__global__ __launch_bounds__(256) void k_utA(const float* __restrict__ U,
                                             const float* __restrict__ A,
                                             const int* __restrict__ Kp,
                                             float* __restrict__ C) {
  __shared__ float Us[256][17];
  int b = blockIdx.x, t = threadIdx.x;
  int K = *Kp; if (K > 16) K = 16;
  const float* Ub = U + (size_t)b * N_ * 16;
  for (int p = 0; p < 16; ++p) {
    int r = (t >> 4) + p * 16, j = t & 15;
    Us[r][j] = Ub[r * 16 + j];
  }
  __syncthreads();
  const float* Ab = A + (size_t)b * NRR;
  float acc[16];
  for (int j = 0; j < 16; ++j) acc[j] = 0.f;
  for (int i = 0; i < N_; ++i) {
    float av = Ab[i * N_ + t];
    for (int j = 0; j < K; ++j) acc[j] += Us[i][j] * av;
  }
  float* Cb = C + (size_t)b * 16 * N_;
  for (int j = 0; j < 16; ++j) Cb[j * N_ + t] = (j < K) ? acc[j] : 0.f;
}

// ---------------------------------------------------------------------------
// Tpnew = U * C   (rank-K outer products), 16 rows per block
// ---------------------------------------------------------------------------
__global__ __launch_bounds__(256) void k_uc(const float* __restrict__ U,
                                            const float* __restrict__ C,
                                            const int* __restrict__ Kp,
                                            float* __restrict__ Tpnew) {
  __shared__ float Cs[16][256];
  __shared__ float Us[16][17];
  int b = blockIdx.y, rt = blockIdx.x * 16, t = threadIdx.x;
  int K = *Kp; if (K > 16) K = 16;
  const float* Cb = C + (size_t)b * 16 * N_;
  for (int j = 0; j < 16; ++j) Cs[j][t] = Cb[j * N_ + t];
  Us[t >> 4][t & 15] = U[(size_t)b * N_ * 16 + (size_t)(rt + (t >> 4)) * 16 + (t & 15)];
  __syncthreads();
  float* Ob = Tpnew + (size_t)b * NRR;
  for (int r = 0; r < 16; ++r) {
    float s = 0.f;
    for (int j = 0; j < K; ++j) s += Us[r][j] * Cs[j][t];
    Ob[(rt + r) * N_ + t] = s;
  }
}

// ---------------------------------------------------------------------------
// copy T to out slot 0
// ---------------------------------------------------------------------------
__global__ __launch_bounds__(256) void k_copyT(const float* __restrict__ T,
                                               float* __restrict__ O) {
  int idx = blockIdx.x * 256 + threadIdx.x;
  if (idx < BRR) O[idx] = T[idx];
}

// ---------------------------------------------------------------------------
// Spnew = Sp - Tpnew + averaging_diagonals(2*Tpnew - Sp). One block/batch.
// ---------------------------------------------------------------------------
__global__ __launch_bounds__(256) void k_spnew(const float* __restrict__ Sp,
                                               const float* __restrict__ Tpnew,
                                               float* __restrict__ Spnew) {
  __shared__ float sums[512];
  int b = blockIdx.x, t = threadIdx.x;
  for (int i = t; i < 512; i += 256) sums[i] = 0.f;
  __syncthreads();
  const float* Spb = Sp + (size_t)b * NRR;
  const float* Tb  = Tpnew + (size_t)b * NRR;
  for (int idx = t; idx < NRR; idx += 256) {
    int r = idx >> 8, c = idx & 255;
    float x = 2.f * Tb[idx] - Spb[idx];
    atomicAdd(&sums[c - r + 255], x);
  }
  __syncthreads();
  for (int d = t; d < 511; d += 256) {
    int cnt = 256 - (d < 255 ? 255 - d : d - 255);
    sums[d] /= (float)cnt;
  }
  __syncthreads();
  float* Ob = Spnew + (size_t)b * NRR;
  for (int idx = t; idx < NRR; idx += 256) {
    int r = idx >> 8, c = idx & 255;
    Ob[idx] = Spb[idx] - Tb[idx] + sums[c - r + 255];
  }
}

// ---------------------------------------------------------------------------
extern "C" void kernel_launch(void* const* d_in, const int* in_sizes, int n_in,
                              void* d_out, int out_size, void* d_ws, size_t ws_size,
                              hipStream_t stream) {
  const float* T  = (const float*)d_in[0];
  const float* Tp = (const float*)d_in[1];
  const float* Sp = (const float*)d_in[2];
  const float* w1 = (const float*)d_in[3];
  const float* w2 = (const float*)d_in[4];
  const float* w3 = (const float*)d_in[5];
  const float* w4 = (const float*)d_in[6];
  const int*   Kp = (const int*)d_in[7];
  float* out = (float*)d_out;

  // d_out doubles as scratch; final contents written at the end in order.
  float* slot0 = out;               // G, then T
  float* slot1 = out + BRR;         // A, then Tpnew
  float* slot2 = out + 2 * (size_t)BRR; // Q/Y + small buffers, then Spnew
  float* G = slot0;
  float* A = slot1;
  float* Qb[2] = { slot2, slot2 + BNL };
  float* sc    = slot2 + 2 * (size_t)BNL;   // 4.19M floats of slack
  float* Mbuf  = sc;
  float* Vbuf  = sc + 524288;
  float* Sbuf  = sc + 2 * 524288;
  float* Lbuf  = sc + 3 * 524288;
  float* Ubuf  = sc + 4 * 524288;
  float* Cbuf  = sc + 5 * 524288;
  int*   topidx = (int*)(sc + 6 * 524288);

  k_build_A<<<BRR / 256, 256, 0, stream>>>(T, Tp, Sp, w1, w2, w3, w4, A);
  k_aat<<<dim3(4, 4, B_), 256, 0, stream>>>(A, G);
  k_init_Y<<<BNL / 256, 256, 0, stream>>>(Qb[0]);

  int cur = 0;
  auto cholqr = [&](int src) -> int {
    k_xty<<<B_, 256, 0, stream>>>(Qb[src], Qb[src], Sbuf);
    k_cholinv<<<B_, 64, 0, stream>>>(Sbuf, Lbuf);
    k_yrinv<<<B_, 256, 0, stream>>>(Qb[src], Lbuf, Qb[1 - src]);
    return 1 - src;
  };
  cur = cholqr(cur);
  for (int it = 0; it < 24; ++it) {
    k_gq<<<dim3(4, B_), 256, 0, stream>>>(G, Qb[cur], Qb[1 - cur]);
    cur = 1 - cur;
    if (it % 3 == 2) cur = cholqr(cur);   // includes it==23 -> final Q orthonormal
  }
  // Rayleigh-Ritz: Z = G*Q, M = Q^T Z
  k_gq<<<dim3(4, B_), 256, 0, stream>>>(G, Qb[cur], Qb[1 - cur]);
  k_xty<<<B_, 256, 0, stream>>>(Qb[cur], Qb[1 - cur], Mbuf);
  k_jacobi<<<B_, 256, 0, stream>>>(Mbuf, Vbuf);
  k_topk<<<B_, 64, 0, stream>>>(Mbuf, Kp, topidx);
  k_formU<<<B_, 256, 0, stream>>>(Qb[cur], Vbuf, topidx, Kp, Ubuf);
  k_utA<<<B_, 256, 0, stream>>>(Ubuf, A, Kp, Cbuf);
  k_uc<<<dim3(16, B_), 256, 0, stream>>>(Ubuf, Cbuf, Kp, slot1);  // overwrites A
  k_copyT<<<BRR / 256, 256, 0, stream>>>(T, slot0);               // overwrites G
  k_spnew<<<B_, 256, 0, stream>>>(Sp, slot1, slot2);              // overwrites Q/Y/scratch
}

// Round 2
// 4652.034 us; speedup vs baseline: 1.2351x; 1.2351x over previous
//
#include <hip/hip_runtime.h>
#include <math.h>

#define B_   128
#define N_   256
#define L_   64
#define NRR  (N_*N_)          // 65536
#define BRR  (B_*NRR)         // 8388608
#define BNL  (B_*N_*L_)       // 2097152

static __device__ __forceinline__ void fma4(float4& a, float s, const float4& v) {
  a.x += s * v.x; a.y += s * v.y; a.z += s * v.z; a.w += s * v.w;
}

// ---------------------------------------------------------------------------
// A = diag(w1)*Sp + diag(w2)*Tp + w4.*Tp + w3.*T   (w1,w2 are diagonal mats)
// ---------------------------------------------------------------------------
__global__ __launch_bounds__(256) void k_build_A(
    const float* __restrict__ T, const float* __restrict__ Tp,
    const float* __restrict__ Sp, const float* __restrict__ w1,
    const float* __restrict__ w2, const float* __restrict__ w3,
    const float* __restrict__ w4, float* __restrict__ A) {
  int i4 = blockIdx.x * 256 + threadIdx.x;
  if (i4 >= BRR / 4) return;
  int rc4 = i4 & (NRR / 4 - 1);
  int r = rc4 >> 6;                 // rc4*4 >> 8
  float a1 = w1[r * N_ + r], a2 = w2[r * N_ + r];
  float4 sp = ((const float4*)Sp)[i4];
  float4 tp = ((const float4*)Tp)[i4];
  float4 tt = ((const float4*)T)[i4];
  float4 w3v = ((const float4*)w3)[rc4];
  float4 w4v = ((const float4*)w4)[rc4];
  float4 o;
  o.x = a1 * sp.x + a2 * tp.x + w4v.x * tp.x + w3v.x * tt.x;
  o.y = a1 * sp.y + a2 * tp.y + w4v.y * tp.y + w3v.y * tt.y;
  o.z = a1 * sp.z + a2 * tp.z + w4v.z * tp.z + w3v.z * tt.z;
  o.w = a1 * sp.w + a2 * tp.w + w4v.w * tp.w + w3v.w * tt.w;
  ((float4*)A)[i4] = o;
}

// ---------------------------------------------------------------------------
// G = A * A^T  (batched 256x256x256), 64x64 tile, transposed LDS + b128 reads.
// Symmetric: compute upper tiles, mirror lower.
// ---------------------------------------------------------------------------
__global__ __launch_bounds__(256) void k_aat(const float* __restrict__ A,
                                             float* __restrict__ G) {
  int b = blockIdx.z, ti = blockIdx.x, tj = blockIdx.y;
  if (ti > tj) return;
  int it = ti * 64, jt = tj * 64;
  __shared__ __align__(16) float AsT[32][68];
  __shared__ __align__(16) float BsT[32][68];
  const float* Ab = A + (size_t)b * NRR;
  int t = threadIdx.x, tx = t & 15, ty = t >> 4;
  float4 acc[4] = {};
  int kk = t & 31, r0 = t >> 5;
  for (int k0 = 0; k0 < N_; k0 += 32) {
#pragma unroll
    for (int p = 0; p < 8; ++p) {
      int r = r0 + p * 8;
      AsT[kk][r] = Ab[(it + r) * N_ + k0 + kk];
      BsT[kk][r] = Ab[(jt + r) * N_ + k0 + kk];
    }
    __syncthreads();
#pragma unroll
    for (int k = 0; k < 32; ++k) {
      float4 av = *(const float4*)&AsT[k][ty * 4];
      float4 bv = *(const float4*)&BsT[k][tx * 4];
      fma4(acc[0], av.x, bv);
      fma4(acc[1], av.y, bv);
      fma4(acc[2], av.z, bv);
      fma4(acc[3], av.w, bv);
    }
    __syncthreads();
  }
  float* Gb = G + (size_t)b * NRR;
#pragma unroll
  for (int i = 0; i < 4; ++i)
    *(float4*)&Gb[(it + ty * 4 + i) * N_ + jt + tx * 4] = acc[i];
  if (ti < tj) {
    const float* a = (const float*)acc;
#pragma unroll
    for (int i = 0; i < 4; ++i)
#pragma unroll
      for (int j = 0; j < 4; ++j)
        Gb[(jt + tx * 4 + j) * N_ + it + ty * 4 + i] = a[i * 4 + j];
  }
}

// ---------------------------------------------------------------------------
// Y = G * Q  (256x256 x 256x64), 64-row tile per block, b128 LDS reads
// ---------------------------------------------------------------------------
__global__ __launch_bounds__(256) void k_gq(const float* __restrict__ G,
                                            const float* __restrict__ Q,
                                            float* __restrict__ Y) {
  __shared__ __align__(16) float GsT[32][68];
  __shared__ __align__(16) float Qs[32][68];
  int b = blockIdx.y, it = blockIdx.x * 64;
  const float* Gb = G + (size_t)b * NRR;
  const float* Qb = Q + (size_t)b * (N_ * L_);
  int t = threadIdx.x, tx = t & 15, ty = t >> 4;
  float4 acc[4] = {};
  int kk = t & 31, r0 = t >> 5;
  int cq = t & 63, kq0 = t >> 6;
  for (int k0 = 0; k0 < N_; k0 += 32) {
#pragma unroll
    for (int p = 0; p < 8; ++p) {
      int r = r0 + p * 8;
      GsT[kk][r] = Gb[(it + r) * N_ + k0 + kk];
    }
#pragma unroll
    for (int p = 0; p < 8; ++p) {
      int k = kq0 + p * 4;
      Qs[k][cq] = Qb[(k0 + k) * L_ + cq];
    }
    __syncthreads();
#pragma unroll
    for (int k = 0; k < 32; ++k) {
      float4 gv = *(const float4*)&GsT[k][ty * 4];
      float4 qv = *(const float4*)&Qs[k][tx * 4];
      fma4(acc[0], gv.x, qv);
      fma4(acc[1], gv.y, qv);
      fma4(acc[2], gv.z, qv);
      fma4(acc[3], gv.w, qv);
    }
    __syncthreads();
  }
  float* Yb = Y + (size_t)b * (N_ * L_);
#pragma unroll
  for (int i = 0; i < 4; ++i)
    *(float4*)&Yb[(it + ty * 4 + i) * L_ + tx * 4] = acc[i];
}

// ---------------------------------------------------------------------------
// M = X^T * Y  (256x64 each -> 64x64), one block per batch, b128 LDS reads
// ---------------------------------------------------------------------------
__global__ __launch_bounds__(256) void k_xty(const float* __restrict__ X,
                                             const float* __restrict__ Y,
                                             float* __restrict__ Mo) {
  __shared__ __align__(16) float Xs[32][68];
  __shared__ __align__(16) float Ys[32][68];
  int b = blockIdx.x;
  const float* Xb = X + (size_t)b * (N_ * L_);
  const float* Yb = Y + (size_t)b * (N_ * L_);
  int t = threadIdx.x, tx = t & 15, ty = t >> 4;
  float4 acc[4] = {};
  int cq = t & 63, kq0 = t >> 6;
  for (int k0 = 0; k0 < N_; k0 += 32) {
#pragma unroll
    for (int p = 0; p < 8; ++p) {
      int k = kq0 + p * 4;
      Xs[k][cq] = Xb[(k0 + k) * L_ + cq];
      Ys[k][cq] = Yb[(k0 + k) * L_ + cq];
    }
    __syncthreads();
#pragma unroll
    for (int k = 0; k < 32; ++k) {
      float4 xv = *(const float4*)&Xs[k][ty * 4];
      float4 yv = *(const float4*)&Ys[k][tx * 4];
      fma4(acc[0], xv.x, yv);
      fma4(acc[1], xv.y, yv);
      fma4(acc[2], xv.z, yv);
      fma4(acc[3], xv.w, yv);
    }
    __syncthreads();
  }
  float* Mb = Mo + (size_t)b * L_ * L_;
#pragma unroll
  for (int i = 0; i < 4; ++i)
    *(float4*)&Mb[(ty * 4 + i) * L_ + tx * 4] = acc[i];
}

// ---------------------------------------------------------------------------
// deterministic pseudo-random init for Y0
// ---------------------------------------------------------------------------
__global__ __launch_bounds__(256) void k_init_Y(float* __restrict__ Y) {
  int idx = blockIdx.x * 256 + threadIdx.x;
  if (idx >= BNL) return;
  unsigned u = (unsigned)idx * 2654435761u;
  u ^= u >> 16; u *= 2246822519u; u ^= u >> 13; u *= 3266489917u; u ^= u >> 16;
  Y[idx] = (float)(int)u * 4.6566129e-10f;
}

// ---------------------------------------------------------------------------
// Cholesky of S (64x64 SPD) + inversion of lower factor. 64 threads/block.
// ---------------------------------------------------------------------------
__global__ __launch_bounds__(64) void k_cholinv(const float* __restrict__ Sg,
                                                float* __restrict__ Linvg) {
  __shared__ float a[64][65];
  __shared__ float li[64][65];
  int b = blockIdx.x, t = threadIdx.x;
  const float* Sb = Sg + (size_t)b * L_ * L_;
  for (int r = 0; r < 64; ++r) { a[r][t] = Sb[r * L_ + t]; li[r][t] = 0.f; }
  __syncthreads();
  for (int j = 0; j < 64; ++j) {
    if (t == j) a[j][j] = sqrtf(fmaxf(a[j][j], 1e-20f));
    __syncthreads();
    float dinv = 1.f / a[j][j];
    if (t > j) a[t][j] *= dinv;
    __syncthreads();
    if (t > j) {
      float lij = a[t][j];
      for (int k = j + 1; k <= t; ++k) a[t][k] -= lij * a[k][j];
    }
    __syncthreads();
  }
  {
    int c = t;
    li[c][c] = 1.f / a[c][c];
    for (int i = c + 1; i < 64; ++i) {
      float s = 0.f;
      for (int k = c; k < i; ++k) s += a[i][k] * li[k][c];
      li[i][c] = -s / a[i][i];
    }
  }
  __syncthreads();
  float* Lb = Linvg + (size_t)b * L_ * L_;
  for (int r = 0; r < 64; ++r) Lb[r * L_ + t] = li[r][t];
}

// ---------------------------------------------------------------------------
// Q = Y * Linv^T   (CholQR apply). One row of Y per thread.
// ---------------------------------------------------------------------------
__global__ __launch_bounds__(256) void k_yrinv(const float* __restrict__ Y,
                                               const float* __restrict__ Linv,
                                               float* __restrict__ Q) {
  __shared__ float Li[64][65];
  int b = blockIdx.x, t = threadIdx.x;
  const float* Lb = Linv + (size_t)b * L_ * L_;
  for (int p = 0; p < 16; ++p) {
    int r = (t >> 6) + p * 4, c = t & 63;
    Li[r][c] = Lb[r * L_ + c];
  }
  __syncthreads();
  const float* Yb = Y + (size_t)b * N_ * L_;
  float* Qb = Q + (size_t)b * N_ * L_;
  float yv[64];
#pragma unroll
  for (int k = 0; k < 64; ++k) yv[k] = Yb[t * L_ + k];
  for (int j = 0; j < 64; ++j) {
    float s = 0.f;
    for (int k = 0; k <= j; ++k) s += yv[k] * Li[j][k];
    Qb[t * L_ + j] = s;
  }
}

// ---------------------------------------------------------------------------
// parallel cyclic Jacobi, SINGLE WAVE per batch. Stores V^T so the V update
// (V <- V J) becomes a row op (Vt <- J^T Vt) and vectorizes as float4.
// Writes eigenvalues (diag) into Mg's diagonal and Vt into Vg.
// ---------------------------------------------------------------------------
__global__ __launch_bounds__(64) void k_jacobi(float* __restrict__ Mg,
                                               float* __restrict__ Vg) {
  __shared__ __align__(16) float A[64][68];
  __shared__ __align__(16) float Vt[64][68];
  __shared__ float cs[32], sn[32];
  __shared__ int   pp[32], qq[32];
  int b = blockIdx.x, t = threadIdx.x;
  float* Mb = Mg + (size_t)b * L_ * L_;
  for (int r = 0; r < 64; ++r) {
    A[r][t]  = Mb[r * L_ + t];
    Vt[r][t] = (r == t) ? 1.f : 0.f;
  }
  __syncthreads();
  int m = t >> 1, h = t & 1;
  for (int sweep = 0; sweep < 7; ++sweep) {
    for (int rnd = 0; rnd < 63; ++rnd) {
      if (t < 32) {
        int p, q;
        if (t == 0) { p = 63; q = rnd; }
        else { p = (rnd + t) % 63; q = (rnd + 63 - t) % 63; }
        int i = min(p, q), j = max(p, q);
        float aii = A[i][i], ajj = A[j][j], aij = A[i][j];
        float c_ = 1.f, s_ = 0.f;
        if (fabsf(aij) > 1e-12f) {
          float tau = (ajj - aii) / (2.f * aij);
          float tt = (tau >= 0.f ? 1.f : -1.f) / (fabsf(tau) + sqrtf(1.f + tau * tau));
          c_ = rsqrtf(1.f + tt * tt);
          s_ = tt * c_;
        }
        pp[t] = i; qq[t] = j; cs[t] = c_; sn[t] = s_;
      }
      __syncthreads();
      int i = pp[m], j = qq[m];
      float c_ = cs[m], s_ = sn[m];
      // row phase: A <- J^T A ; Vt <- J^T Vt   (vectorized, half-rows per lane)
      {
        float4* Ai = (float4*)&A[i][h * 32];
        float4* Aj = (float4*)&A[j][h * 32];
        float4* Vi = (float4*)&Vt[i][h * 32];
        float4* Vj = (float4*)&Vt[j][h * 32];
#pragma unroll
        for (int u = 0; u < 8; ++u) {
          float4 x = Ai[u], y = Aj[u];
          float4 nx, ny;
          nx.x = c_ * x.x - s_ * y.x; ny.x = s_ * x.x + c_ * y.x;
          nx.y = c_ * x.y - s_ * y.y; ny.y = s_ * x.y + c_ * y.y;
          nx.z = c_ * x.z - s_ * y.z; ny.z = s_ * x.z + c_ * y.z;
          nx.w = c_ * x.w - s_ * y.w; ny.w = s_ * x.w + c_ * y.w;
          Ai[u] = nx; Aj[u] = ny;
          float4 vx = Vi[u], vy = Vj[u];
          float4 mx, my;
          mx.x = c_ * vx.x - s_ * vy.x; my.x = s_ * vx.x + c_ * vy.x;
          mx.y = c_ * vx.y - s_ * vy.y; my.y = s_ * vx.y + c_ * vy.y;
          mx.z = c_ * vx.z - s_ * vy.z; my.z = s_ * vx.z + c_ * vy.z;
          mx.w = c_ * vx.w - s_ * vy.w; my.w = s_ * vx.w + c_ * vy.w;
          Vi[u] = mx; Vj[u] = my;
        }
      }
      __syncthreads();
      // col phase: A <- A J   (scalar, half-columns per lane)
#pragma unroll 8
      for (int kk = 0; kk < 32; ++kk) {
        int k = h * 32 + kk;
        float x = A[k][i], y = A[k][j];
        A[k][i] = c_ * x - s_ * y;
        A[k][j] = s_ * x + c_ * y;
      }
      __syncthreads();
    }
  }
  // write back: eigenvalues on diag of Mg; Vt (V transposed) to Vg
  Mb[t * L_ + t] = A[t][t];
  float* Vb = Vg + (size_t)b * L_ * L_;
  for (int r = 0; r < 64; ++r) Vb[r * L_ + t] = Vt[r][t];
}

// ---------------------------------------------------------------------------
// pick indices of K largest eigenvalues (diag of M)
// ---------------------------------------------------------------------------
__global__ void k_topk(const float* __restrict__ Mg, const int* __restrict__ Kp,
                       int* __restrict__ topidx) {
  int b = blockIdx.x;
  if (threadIdx.x != 0) return;
  const float* Mb = Mg + (size_t)b * L_ * L_;
  int K = *Kp; if (K > 16) K = 16;
  float vals[64]; bool used[64];
  for (int i = 0; i < 64; ++i) { vals[i] = Mb[i * L_ + i]; used[i] = false; }
  for (int j = 0; j < K; ++j) {
    int best = 0; float bv = -1e30f;
    for (int i = 0; i < 64; ++i)
      if (!used[i] && vals[i] > bv) { bv = vals[i]; best = i; }
    used[best] = true;
    topidx[b * 16 + j] = best;
  }
}

// ---------------------------------------------------------------------------
// U = Q * V[:, topidx]   (256x64 x 64xK)   -- V passed TRANSPOSED (Vt rows)
// ---------------------------------------------------------------------------
__global__ __launch_bounds__(256) void k_formU(const float* __restrict__ Q,
                                               const float* __restrict__ Vtg,
                                               const int* __restrict__ topidx,
                                               const int* __restrict__ Kp,
                                               float* __restrict__ U) {
  __shared__ float Vs[64][17];
  int b = blockIdx.x, t = threadIdx.x;
  int K = *Kp; if (K > 16) K = 16;
  if (t < 64) {
    for (int j = 0; j < 16; ++j)
      Vs[t][j] = (j < K)
        ? Vtg[(size_t)b * L_ * L_ + (size_t)topidx[b * 16 + j] * L_ + t]
        : 0.f;
  }
  __syncthreads();
  const float* Qb = Q + (size_t)b * N_ * L_;
  float qv[64];
#pragma unroll
  for (int k = 0; k < 64; ++k) qv[k] = Qb[t * L_ + k];
  float* Ub = U + (size_t)b * N_ * 16;
  for (int j = 0; j < 16; ++j) {
    float s = 0.f;
    if (j < K) {
#pragma unroll
      for (int k = 0; k < 64; ++k) s += qv[k] * Vs[k][j];
    }
    Ub[t * 16 + j] = s;
  }
}

// ---------------------------------------------------------------------------
// C = U^T * A   (Kx256 = sum over 256 rows)
// ---------------------------------------------------------------------------
__global__ __launch_bounds__(256) void k_utA(const float* __restrict__ U,
                                             const float* __restrict__ A,
                                             const int* __restrict__ Kp,
                                             float* __restrict__ C) {
  __shared__ float Us[256][17];
  int b = blockIdx.x, t = threadIdx.x;
  int K = *Kp; if (K > 16) K = 16;
  const float* Ub = U + (size_t)b * N_ * 16;
  for (int p = 0; p < 16; ++p) {
    int r = (t >> 4) + p * 16, j = t & 15;
    Us[r][j] = Ub[r * 16 + j];
  }
  __syncthreads();
  const float* Ab = A + (size_t)b * NRR;
  float acc[16];
  for (int j = 0; j < 16; ++j) acc[j] = 0.f;
  for (int i = 0; i < N_; ++i) {
    float av = Ab[i * N_ + t];
    for (int j = 0; j < K; ++j) acc[j] += Us[i][j] * av;
  }
  float* Cb = C + (size_t)b * 16 * N_;
  for (int j = 0; j < 16; ++j) Cb[j * N_ + t] = (j < K) ? acc[j] : 0.f;
}

// ---------------------------------------------------------------------------
// Tpnew = U * C   (rank-K outer products), 16 rows per block
// ---------------------------------------------------------------------------
__global__ __launch_bounds__(256) void k_uc(const float* __restrict__ U,
                                            const float* __restrict__ C,
                                            const int* __restrict__ Kp,
                                            float* __restrict__ Tpnew) {
  __shared__ float Cs[16][256];
  __shared__ float Us[16][17];
  int b = blockIdx.y, rt = blockIdx.x * 16, t = threadIdx.x;
  int K = *Kp; if (K > 16) K = 16;
  const float* Cb = C + (size_t)b * 16 * N_;
  for (int j = 0; j < 16; ++j) Cs[j][t] = Cb[j * N_ + t];
  Us[t >> 4][t & 15] = U[(size_t)b * N_ * 16 + (size_t)(rt + (t >> 4)) * 16 + (t & 15)];
  __syncthreads();
  float* Ob = Tpnew + (size_t)b * NRR;
  for (int r = 0; r < 16; ++r) {
    float s = 0.f;
    for (int j = 0; j < K; ++j) s += Us[r][j] * Cs[j][t];
    Ob[(rt + r) * N_ + t] = s;
  }
}

// ---------------------------------------------------------------------------
// copy T to out slot 0 (vectorized)
// ---------------------------------------------------------------------------
__global__ __launch_bounds__(256) void k_copyT(const float* __restrict__ T,
                                               float* __restrict__ O) {
  int i4 = blockIdx.x * 256 + threadIdx.x;
  if (i4 < BRR / 4) ((float4*)O)[i4] = ((const float4*)T)[i4];
}

// ---------------------------------------------------------------------------
// Spnew = Sp - Tpnew + averaging_diagonals(2*Tpnew - Sp). One block/batch.
// ---------------------------------------------------------------------------
__global__ __launch_bounds__(256) void k_spnew(const float* __restrict__ Sp,
                                               const float* __restrict__ Tpnew,
                                               float* __restrict__ Spnew) {
  __shared__ float sums[512];
  int b = blockIdx.x, t = threadIdx.x;
  for (int i = t; i < 512; i += 256) sums[i] = 0.f;
  __syncthreads();
  const float4* Spb = (const float4*)(Sp + (size_t)b * NRR);
  const float4* Tb  = (const float4*)(Tpnew + (size_t)b * NRR);
  for (int i4 = t; i4 < NRR / 4; i4 += 256) {
    int r = i4 >> 6, c = (i4 & 63) * 4;
    float4 tv = Tb[i4], sv = Spb[i4];
    int d = c - r + 255;
    atomicAdd(&sums[d + 0], 2.f * tv.x - sv.x);
    atomicAdd(&sums[d + 1], 2.f * tv.y - sv.y);
    atomicAdd(&sums[d + 2], 2.f * tv.z - sv.z);
    atomicAdd(&sums[d + 3], 2.f * tv.w - sv.w);
  }
  __syncthreads();
  for (int d = t; d < 511; d += 256) {
    int cnt = 256 - (d < 255 ? 255 - d : d - 255);
    sums[d] /= (float)cnt;
  }
  __syncthreads();
  float4* Ob = (float4*)(Spnew + (size_t)b * NRR);
  for (int i4 = t; i4 < NRR / 4; i4 += 256) {
    int r = i4 >> 6, c = (i4 & 63) * 4;
    float4 tv = Tb[i4], sv = Spb[i4];
    int d = c - r + 255;
    float4 o;
    o.x = sv.x - tv.x + sums[d + 0];
    o.y = sv.y - tv.y + sums[d + 1];
    o.z = sv.z - tv.z + sums[d + 2];
    o.w = sv.w - tv.w + sums[d + 3];
    Ob[i4] = o;
  }
}

// ---------------------------------------------------------------------------
extern "C" void kernel_launch(void* const* d_in, const int* in_sizes, int n_in,
                              void* d_out, int out_size, void* d_ws, size_t ws_size,
                              hipStream_t stream) {
  const float* T  = (const float*)d_in[0];
  const float* Tp = (const float*)d_in[1];
  const float* Sp = (const float*)d_in[2];
  const float* w1 = (const float*)d_in[3];
  const float* w2 = (const float*)d_in[4];
  const float* w3 = (const float*)d_in[5];
  const float* w4 = (const float*)d_in[6];
  const int*   Kp = (const int*)d_in[7];
  float* out = (float*)d_out;

  float* slot0 = out;                   // G, then T
  float* slot1 = out + BRR;             // A, then Tpnew
  float* slot2 = out + 2 * (size_t)BRR; // Q/Y + small buffers, then Spnew
  float* G = slot0;
  float* A = slot1;
  float* Qb[2] = { slot2, slot2 + BNL };
  float* sc    = slot2 + 2 * (size_t)BNL;
  float* Mbuf  = sc;
  float* Vbuf  = sc + 524288;
  float* Sbuf  = sc + 2 * 524288;
  float* Lbuf  = sc + 3 * 524288;
  float* Ubuf  = sc + 4 * 524288;
  float* Cbuf  = sc + 5 * 524288;
  int*   topidx = (int*)(sc + 6 * 524288);

  k_build_A<<<BRR / 4 / 256, 256, 0, stream>>>(T, Tp, Sp, w1, w2, w3, w4, A);
  k_aat<<<dim3(4, 4, B_), 256, 0, stream>>>(A, G);
  k_init_Y<<<BNL / 256, 256, 0, stream>>>(Qb[0]);

  int cur = 0;
  auto cholqr = [&](int src) -> int {
    k_xty<<<B_, 256, 0, stream>>>(Qb[src], Qb[src], Sbuf);
    k_cholinv<<<B_, 64, 0, stream>>>(Sbuf, Lbuf);
    k_yrinv<<<B_, 256, 0, stream>>>(Qb[src], Lbuf, Qb[1 - src]);
    return 1 - src;
  };
  cur = cholqr(cur);
  for (int it = 0; it < 24; ++it) {
    k_gq<<<dim3(4, B_), 256, 0, stream>>>(G, Qb[cur], Qb[1 - cur]);
    cur = 1 - cur;
    if (it % 4 == 3) cur = cholqr(cur);   // QR at 3,7,11,15,19,23
  }
  // Rayleigh-Ritz: Z = G*Q, M = Q^T Z
  k_gq<<<dim3(4, B_), 256, 0, stream>>>(G, Qb[cur], Qb[1 - cur]);
  k_xty<<<B_, 256, 0, stream>>>(Qb[cur], Qb[1 - cur], Mbuf);
  k_jacobi<<<B_, 64, 0, stream>>>(Mbuf, Vbuf);
  k_topk<<<B_, 64, 0, stream>>>(Mbuf, Kp, topidx);
  k_formU<<<B_, 256, 0, stream>>>(Qb[cur], Vbuf, topidx, Kp, Ubuf);
  k_utA<<<B_, 256, 0, stream>>>(Ubuf, A, Kp, Cbuf);
  k_uc<<<dim3(16, B_), 256, 0, stream>>>(Ubuf, Cbuf, Kp, slot1);  // overwrites A
  k_copyT<<<BRR / 4 / 256, 256, 0, stream>>>(T, slot0);           // overwrites G
  k_spnew<<<B_, 256, 0, stream>>>(Sp, slot1, slot2);              // overwrites scratch
}

// Round 3
// 1750.711 us; speedup vs baseline: 3.2819x; 2.6572x over previous
//
#include <hip/hip_runtime.h>
#include <math.h>

#define B_   128
#define N_   256
#define L_   64
#define NRR  (N_*N_)          // 65536
#define BRR  (B_*NRR)         // 8388608
#define BNL  (B_*N_*L_)       // 2097152

static __device__ __forceinline__ void fma4(float4& a, float s, const float4& v) {
  a.x += s * v.x; a.y += s * v.y; a.z += s * v.z; a.w += s * v.w;
}

// ---------------------------------------------------------------------------
// A = diag(w1)*Sp + diag(w2)*Tp + w4.*Tp + w3.*T
// ---------------------------------------------------------------------------
__global__ __launch_bounds__(256) void k_build_A(
    const float* __restrict__ T, const float* __restrict__ Tp,
    const float* __restrict__ Sp, const float* __restrict__ w1,
    const float* __restrict__ w2, const float* __restrict__ w3,
    const float* __restrict__ w4, float* __restrict__ A) {
  int i4 = blockIdx.x * 256 + threadIdx.x;
  if (i4 >= BRR / 4) return;
  int rc4 = i4 & (NRR / 4 - 1);
  int r = rc4 >> 6;
  float a1 = w1[r * N_ + r], a2 = w2[r * N_ + r];
  float4 sp = ((const float4*)Sp)[i4];
  float4 tp = ((const float4*)Tp)[i4];
  float4 tt = ((const float4*)T)[i4];
  float4 w3v = ((const float4*)w3)[rc4];
  float4 w4v = ((const float4*)w4)[rc4];
  float4 o;
  o.x = a1 * sp.x + a2 * tp.x + w4v.x * tp.x + w3v.x * tt.x;
  o.y = a1 * sp.y + a2 * tp.y + w4v.y * tp.y + w3v.y * tt.y;
  o.z = a1 * sp.z + a2 * tp.z + w4v.z * tp.z + w3v.z * tt.z;
  o.w = a1 * sp.w + a2 * tp.w + w4v.w * tp.w + w3v.w * tt.w;
  ((float4*)A)[i4] = o;
}

// ---------------------------------------------------------------------------
// G = A * A^T  (batched), 64x64 tile, symmetric mirror
// ---------------------------------------------------------------------------
__global__ __launch_bounds__(256) void k_aat(const float* __restrict__ A,
                                             float* __restrict__ G) {
  int b = blockIdx.z, ti = blockIdx.x, tj = blockIdx.y;
  if (ti > tj) return;
  int it = ti * 64, jt = tj * 64;
  __shared__ __align__(16) float AsT[32][68];
  __shared__ __align__(16) float BsT[32][68];
  const float* Ab = A + (size_t)b * NRR;
  int t = threadIdx.x, tx = t & 15, ty = t >> 4;
  float4 acc[4] = {};
  int kk = t & 31, r0 = t >> 5;
  for (int k0 = 0; k0 < N_; k0 += 32) {
#pragma unroll
    for (int p = 0; p < 8; ++p) {
      int r = r0 + p * 8;
      AsT[kk][r] = Ab[(it + r) * N_ + k0 + kk];
      BsT[kk][r] = Ab[(jt + r) * N_ + k0 + kk];
    }
    __syncthreads();
#pragma unroll
    for (int k = 0; k < 32; ++k) {
      float4 av = *(const float4*)&AsT[k][ty * 4];
      float4 bv = *(const float4*)&BsT[k][tx * 4];
      fma4(acc[0], av.x, bv);
      fma4(acc[1], av.y, bv);
      fma4(acc[2], av.z, bv);
      fma4(acc[3], av.w, bv);
    }
    __syncthreads();
  }
  float* Gb = G + (size_t)b * NRR;
#pragma unroll
  for (int i = 0; i < 4; ++i)
    *(float4*)&Gb[(it + ty * 4 + i) * N_ + jt + tx * 4] = acc[i];
  if (ti < tj) {
    const float* a = (const float*)acc;
#pragma unroll
    for (int i = 0; i < 4; ++i)
#pragma unroll
      for (int j = 0; j < 4; ++j)
        Gb[(jt + tx * 4 + j) * N_ + it + ty * 4 + i] = a[i * 4 + j];
  }
}

// ---------------------------------------------------------------------------
// Y = G * Q  (256x256 x 256x64), 64-row tile per block
// ---------------------------------------------------------------------------
__global__ __launch_bounds__(256) void k_gq(const float* __restrict__ G,
                                            const float* __restrict__ Q,
                                            float* __restrict__ Y) {
  __shared__ __align__(16) float GsT[32][68];
  __shared__ __align__(16) float Qs[32][68];
  int b = blockIdx.y, it = blockIdx.x * 64;
  const float* Gb = G + (size_t)b * NRR;
  const float* Qb = Q + (size_t)b * (N_ * L_);
  int t = threadIdx.x, tx = t & 15, ty = t >> 4;
  float4 acc[4] = {};
  int kk = t & 31, r0 = t >> 5;
  int cq = t & 63, kq0 = t >> 6;
  for (int k0 = 0; k0 < N_; k0 += 32) {
#pragma unroll
    for (int p = 0; p < 8; ++p) {
      int r = r0 + p * 8;
      GsT[kk][r] = Gb[(it + r) * N_ + k0 + kk];
    }
#pragma unroll
    for (int p = 0; p < 8; ++p) {
      int k = kq0 + p * 4;
      Qs[k][cq] = Qb[(k0 + k) * L_ + cq];
    }
    __syncthreads();
#pragma unroll
    for (int k = 0; k < 32; ++k) {
      float4 gv = *(const float4*)&GsT[k][ty * 4];
      float4 qv = *(const float4*)&Qs[k][tx * 4];
      fma4(acc[0], gv.x, qv);
      fma4(acc[1], gv.y, qv);
      fma4(acc[2], gv.z, qv);
      fma4(acc[3], gv.w, qv);
    }
    __syncthreads();
  }
  float* Yb = Y + (size_t)b * (N_ * L_);
#pragma unroll
  for (int i = 0; i < 4; ++i)
    *(float4*)&Yb[(it + ty * 4 + i) * L_ + tx * 4] = acc[i];
}

// ---------------------------------------------------------------------------
// M = X^T * Y  (256x64 each -> 64x64), one block per batch
// ---------------------------------------------------------------------------
__global__ __launch_bounds__(256) void k_xty(const float* __restrict__ X,
                                             const float* __restrict__ Y,
                                             float* __restrict__ Mo) {
  __shared__ __align__(16) float Xs[32][68];
  __shared__ __align__(16) float Ys[32][68];
  int b = blockIdx.x;
  const float* Xb = X + (size_t)b * (N_ * L_);
  const float* Yb = Y + (size_t)b * (N_ * L_);
  int t = threadIdx.x, tx = t & 15, ty = t >> 4;
  float4 acc[4] = {};
  int cq = t & 63, kq0 = t >> 6;
  for (int k0 = 0; k0 < N_; k0 += 32) {
#pragma unroll
    for (int p = 0; p < 8; ++p) {
      int k = kq0 + p * 4;
      Xs[k][cq] = Xb[(k0 + k) * L_ + cq];
      Ys[k][cq] = Yb[(k0 + k) * L_ + cq];
    }
    __syncthreads();
#pragma unroll
    for (int k = 0; k < 32; ++k) {
      float4 xv = *(const float4*)&Xs[k][ty * 4];
      float4 yv = *(const float4*)&Ys[k][tx * 4];
      fma4(acc[0], xv.x, yv);
      fma4(acc[1], xv.y, yv);
      fma4(acc[2], xv.z, yv);
      fma4(acc[3], xv.w, yv);
    }
    __syncthreads();
  }
  float* Mb = Mo + (size_t)b * L_ * L_;
#pragma unroll
  for (int i = 0; i < 4; ++i)
    *(float4*)&Mb[(ty * 4 + i) * L_ + tx * 4] = acc[i];
}

// ---------------------------------------------------------------------------
// deterministic pseudo-random init for Y0
// ---------------------------------------------------------------------------
__global__ __launch_bounds__(256) void k_init_Y(float* __restrict__ Y) {
  int idx = blockIdx.x * 256 + threadIdx.x;
  if (idx >= BNL) return;
  unsigned u = (unsigned)idx * 2654435761u;
  u ^= u >> 16; u *= 2246822519u; u ^= u >> 13; u *= 3266489917u; u ^= u >> 16;
  Y[idx] = (float)(int)u * 4.6566129e-10f;
}

// ---------------------------------------------------------------------------
// Fused CholQR: in-place orthonormalization of one 256x64 panel per block.
// Panel -> LDS, S = P^T P, right-looking Cholesky (256-thr trailing update),
// row-per-thread TRSM with register solve, store back.
// ---------------------------------------------------------------------------
__global__ __launch_bounds__(256) void k_qr(float* __restrict__ Q) {
  __shared__ __align__(16) float P[256][68];
  __shared__ __align__(16) float S[64][68];
  __shared__ float dinv[64];
  int b = blockIdx.x, t = threadIdx.x;
  float* Qb = Q + (size_t)b * (N_ * L_);
  // load panel (coalesced float4)
#pragma unroll
  for (int p = 0; p < 16; ++p) {
    int i4 = t + p * 256;
    int r = i4 >> 4, u = i4 & 15;
    *(float4*)&P[r][u * 4] = ((const float4*)Qb)[i4];
  }
  __syncthreads();
  // S = P^T P (16x16 thread grid, 4x4 acc each)
  {
    int tx = t & 15, ty = t >> 4;
    float4 a0 = {}, a1 = {}, a2 = {}, a3 = {};
    for (int k = 0; k < 256; ++k) {
      float4 av = *(const float4*)&P[k][ty * 4];
      float4 bv = *(const float4*)&P[k][tx * 4];
      fma4(a0, av.x, bv); fma4(a1, av.y, bv);
      fma4(a2, av.z, bv); fma4(a3, av.w, bv);
    }
    *(float4*)&S[ty * 4 + 0][tx * 4] = a0;
    *(float4*)&S[ty * 4 + 1][tx * 4] = a1;
    *(float4*)&S[ty * 4 + 2][tx * 4] = a2;
    *(float4*)&S[ty * 4 + 3][tx * 4] = a3;
  }
  __syncthreads();
  // Cholesky, right-looking; lower triangle of S becomes L
  for (int j = 0; j < 64; ++j) {
    if (t == 0) {
      float d = sqrtf(fmaxf(S[j][j], 1e-20f));
      S[j][j] = d; dinv[j] = 1.f / d;
    }
    __syncthreads();
    if (t > j && t < 64) S[t][j] *= dinv[j];
    __syncthreads();
    int nrows = 63 - j;
    for (int e = t; e < nrows * 64; e += 256) {
      int i = j + 1 + (e >> 6), k = e & 63;
      if (k > j && k <= i) S[i][k] -= S[i][j] * S[k][j];
    }
    __syncthreads();
  }
  // TRSM: row t of panel, solve q L^T = y  (forward substitution, registers)
  {
    float x[64];
#pragma unroll
    for (int u = 0; u < 16; ++u) {
      float4 v = *(const float4*)&P[t][u * 4];
      x[u * 4 + 0] = v.x; x[u * 4 + 1] = v.y;
      x[u * 4 + 2] = v.z; x[u * 4 + 3] = v.w;
    }
#pragma unroll
    for (int j = 0; j < 64; ++j) {
      float s = x[j];
#pragma unroll
      for (int mq = 0; mq < (j >> 2); ++mq) {
        float4 lv = *(const float4*)&S[j][mq * 4];
        s -= lv.x * x[mq * 4 + 0] + lv.y * x[mq * 4 + 1]
           + lv.z * x[mq * 4 + 2] + lv.w * x[mq * 4 + 3];
      }
#pragma unroll
      for (int k = (j & ~3); k < j; ++k) s -= S[j][k] * x[k];
      x[j] = s * dinv[j];
    }
#pragma unroll
    for (int u = 0; u < 16; ++u) {
      float4 v;
      v.x = x[u * 4 + 0]; v.y = x[u * 4 + 1];
      v.z = x[u * 4 + 2]; v.w = x[u * 4 + 3];
      *(float4*)&Qb[t * L_ + u * 4] = v;
    }
  }
}

// ---------------------------------------------------------------------------
// parallel cyclic Jacobi, 256 threads (4 waves) per batch.
// A[64][68] + Vt[64][68]; float4 row phase (A & Vt fused), scalar col phase.
// 3 barriers/round, 5 sweeps. Writes diag(eigvals) into Mg, Vt into Vg.
// ---------------------------------------------------------------------------
__global__ __launch_bounds__(256) void k_jacobi(float* __restrict__ Mg,
                                                float* __restrict__ Vg) {
  __shared__ __align__(16) float A[64][68];
  __shared__ __align__(16) float Vt[64][68];
  __shared__ float cs[32], sn[32];
  int b = blockIdx.x, t = threadIdx.x;
  float* Mb = Mg + (size_t)b * L_ * L_;
#pragma unroll
  for (int p = 0; p < 16; ++p) {
    int e = t + p * 256, r = e >> 6, c = e & 63;
    A[r][c] = Mb[r * L_ + c];
    Vt[r][c] = (r == c) ? 1.f : 0.f;
  }
  __syncthreads();
  int m = t >> 3, u = t & 7;
  for (int sweep = 0; sweep < 5; ++sweep) {
    for (int rnd = 0; rnd < 63; ++rnd) {
      // param phase: lane-per-pair (t<32)
      if (t < 32) {
        int i2, j2;
        if (t == 0) { i2 = rnd; j2 = 63; }
        else {
          int a = rnd + t;       if (a >= 63) a -= 63;
          int bb = rnd + 63 - t; if (bb >= 63) bb -= 63;
          i2 = min(a, bb); j2 = max(a, bb);
        }
        float aii = A[i2][i2], ajj = A[j2][j2], aij = A[i2][j2];
        float c_ = 1.f, s_ = 0.f;
        if (fabsf(aij) > 1e-12f) {
          float tau = (ajj - aii) / (2.f * aij);
          float tt = (tau >= 0.f ? 1.f : -1.f) / (fabsf(tau) + sqrtf(1.f + tau * tau));
          c_ = rsqrtf(1.f + tt * tt);
          s_ = tt * c_;
        }
        cs[t] = c_; sn[t] = s_;
      }
      __syncthreads();
      // every thread recomputes its pair (m) schedule
      int i, j;
      if (m == 0) { i = rnd; j = 63; }
      else {
        int a = rnd + m;       if (a >= 63) a -= 63;
        int bb = rnd + 63 - m; if (bb >= 63) bb -= 63;
        i = min(a, bb); j = max(a, bb);
      }
      float c_ = cs[m], s_ = sn[m];
      // row phase: A <- J^T A ; Vt <- J^T Vt  (thread t handles cols 8u..8u+7)
      {
        float4* Ai = (float4*)&A[i][u * 8];
        float4* Aj = (float4*)&A[j][u * 8];
        float4* Vi = (float4*)&Vt[i][u * 8];
        float4* Vj = (float4*)&Vt[j][u * 8];
#pragma unroll
        for (int q = 0; q < 2; ++q) {
          float4 x = Ai[q], y = Aj[q], nx, ny;
          nx.x = c_ * x.x - s_ * y.x; ny.x = s_ * x.x + c_ * y.x;
          nx.y = c_ * x.y - s_ * y.y; ny.y = s_ * x.y + c_ * y.y;
          nx.z = c_ * x.z - s_ * y.z; ny.z = s_ * x.z + c_ * y.z;
          nx.w = c_ * x.w - s_ * y.w; ny.w = s_ * x.w + c_ * y.w;
          Ai[q] = nx; Aj[q] = ny;
          float4 vx = Vi[q], vy = Vj[q], mx, my;
          mx.x = c_ * vx.x - s_ * vy.x; my.x = s_ * vx.x + c_ * vy.x;
          mx.y = c_ * vx.y - s_ * vy.y; my.y = s_ * vx.y + c_ * vy.y;
          mx.z = c_ * vx.z - s_ * vy.z; my.z = s_ * vx.z + c_ * vy.z;
          mx.w = c_ * vx.w - s_ * vy.w; my.w = s_ * vx.w + c_ * vy.w;
          Vi[q] = mx; Vj[q] = my;
        }
      }
      __syncthreads();
      // col phase: A <- A J  (thread t handles rows u, u+8, ..., u+56)
#pragma unroll
      for (int p = 0; p < 8; ++p) {
        int k = u + 8 * p;
        float x = A[k][i], y = A[k][j];
        A[k][i] = c_ * x - s_ * y;
        A[k][j] = s_ * x + c_ * y;
      }
      __syncthreads();
    }
  }
  if (t < 64) Mb[t * L_ + t] = A[t][t];
  float* Vb = Vg + (size_t)b * L_ * L_;
#pragma unroll
  for (int p = 0; p < 16; ++p) {
    int e = t + p * 256, r = e >> 6, c = e & 63;
    Vb[r * L_ + c] = Vt[r][c];
  }
}

// ---------------------------------------------------------------------------
// pick indices of K largest eigenvalues (diag of M)
// ---------------------------------------------------------------------------
__global__ void k_topk(const float* __restrict__ Mg, const int* __restrict__ Kp,
                       int* __restrict__ topidx) {
  int b = blockIdx.x;
  if (threadIdx.x != 0) return;
  const float* Mb = Mg + (size_t)b * L_ * L_;
  int K = *Kp; if (K > 16) K = 16;
  float vals[64]; bool used[64];
  for (int i = 0; i < 64; ++i) { vals[i] = Mb[i * L_ + i]; used[i] = false; }
  for (int j = 0; j < K; ++j) {
    int best = 0; float bv = -1e30f;
    for (int i = 0; i < 64; ++i)
      if (!used[i] && vals[i] > bv) { bv = vals[i]; best = i; }
    used[best] = true;
    topidx[b * 16 + j] = best;
  }
}

// ---------------------------------------------------------------------------
// U = Q * V[:, topidx]   (V passed transposed: Vt rows are eigenvectors)
// ---------------------------------------------------------------------------
__global__ __launch_bounds__(256) void k_formU(const float* __restrict__ Q,
                                               const float* __restrict__ Vtg,
                                               const int* __restrict__ topidx,
                                               const int* __restrict__ Kp,
                                               float* __restrict__ U) {
  __shared__ float Vs[64][17];
  int b = blockIdx.x, t = threadIdx.x;
  int K = *Kp; if (K > 16) K = 16;
  if (t < 64) {
    for (int j = 0; j < 16; ++j)
      Vs[t][j] = (j < K)
        ? Vtg[(size_t)b * L_ * L_ + (size_t)topidx[b * 16 + j] * L_ + t]
        : 0.f;
  }
  __syncthreads();
  const float* Qb = Q + (size_t)b * N_ * L_;
  float qv[64];
#pragma unroll
  for (int k = 0; k < 64; ++k) qv[k] = Qb[t * L_ + k];
  float* Ub = U + (size_t)b * N_ * 16;
  for (int j = 0; j < 16; ++j) {
    float s = 0.f;
    if (j < K) {
#pragma unroll
      for (int k = 0; k < 64; ++k) s += qv[k] * Vs[k][j];
    }
    Ub[t * 16 + j] = s;
  }
}

// ---------------------------------------------------------------------------
// C = U^T * A   (Kx256)
// ---------------------------------------------------------------------------
__global__ __launch_bounds__(256) void k_utA(const float* __restrict__ U,
                                             const float* __restrict__ A,
                                             const int* __restrict__ Kp,
                                             float* __restrict__ C) {
  __shared__ float Us[256][17];
  int b = blockIdx.x, t = threadIdx.x;
  int K = *Kp; if (K > 16) K = 16;
  const float* Ub = U + (size_t)b * N_ * 16;
  for (int p = 0; p < 16; ++p) {
    int r = (t >> 4) + p * 16, j = t & 15;
    Us[r][j] = Ub[r * 16 + j];
  }
  __syncthreads();
  const float* Ab = A + (size_t)b * NRR;
  float acc[16];
  for (int j = 0; j < 16; ++j) acc[j] = 0.f;
  for (int i = 0; i < N_; ++i) {
    float av = Ab[i * N_ + t];
    for (int j = 0; j < K; ++j) acc[j] += Us[i][j] * av;
  }
  float* Cb = C + (size_t)b * 16 * N_;
  for (int j = 0; j < 16; ++j) Cb[j * N_ + t] = (j < K) ? acc[j] : 0.f;
}

// ---------------------------------------------------------------------------
// Tpnew = U * C   (rank-K), 16 rows per block
// ---------------------------------------------------------------------------
__global__ __launch_bounds__(256) void k_uc(const float* __restrict__ U,
                                            const float* __restrict__ C,
                                            const int* __restrict__ Kp,
                                            float* __restrict__ Tpnew) {
  __shared__ float Cs[16][256];
  __shared__ float Us[16][17];
  int b = blockIdx.y, rt = blockIdx.x * 16, t = threadIdx.x;
  int K = *Kp; if (K > 16) K = 16;
  const float* Cb = C + (size_t)b * 16 * N_;
  for (int j = 0; j < 16; ++j) Cs[j][t] = Cb[j * N_ + t];
  Us[t >> 4][t & 15] = U[(size_t)b * N_ * 16 + (size_t)(rt + (t >> 4)) * 16 + (t & 15)];
  __syncthreads();
  float* Ob = Tpnew + (size_t)b * NRR;
  for (int r = 0; r < 16; ++r) {
    float s = 0.f;
    for (int j = 0; j < K; ++j) s += Us[r][j] * Cs[j][t];
    Ob[(rt + r) * N_ + t] = s;
  }
}

// ---------------------------------------------------------------------------
// copy T to out slot 0
// ---------------------------------------------------------------------------
__global__ __launch_bounds__(256) void k_copyT(const float* __restrict__ T,
                                               float* __restrict__ O) {
  int i4 = blockIdx.x * 256 + threadIdx.x;
  if (i4 < BRR / 4) ((float4*)O)[i4] = ((const float4*)T)[i4];
}

// ---------------------------------------------------------------------------
// Spnew = Sp - Tpnew + averaging_diagonals(2*Tpnew - Sp). One block/batch.
// ---------------------------------------------------------------------------
__global__ __launch_bounds__(256) void k_spnew(const float* __restrict__ Sp,
                                               const float* __restrict__ Tpnew,
                                               float* __restrict__ Spnew) {
  __shared__ float sums[512];
  int b = blockIdx.x, t = threadIdx.x;
  for (int i = t; i < 512; i += 256) sums[i] = 0.f;
  __syncthreads();
  const float4* Spb = (const float4*)(Sp + (size_t)b * NRR);
  const float4* Tb  = (const float4*)(Tpnew + (size_t)b * NRR);
  for (int i4 = t; i4 < NRR / 4; i4 += 256) {
    int r = i4 >> 6, c = (i4 & 63) * 4;
    float4 tv = Tb[i4], sv = Spb[i4];
    int d = c - r + 255;
    atomicAdd(&sums[d + 0], 2.f * tv.x - sv.x);
    atomicAdd(&sums[d + 1], 2.f * tv.y - sv.y);
    atomicAdd(&sums[d + 2], 2.f * tv.z - sv.z);
    atomicAdd(&sums[d + 3], 2.f * tv.w - sv.w);
  }
  __syncthreads();
  for (int d = t; d < 511; d += 256) {
    int cnt = 256 - (d < 255 ? 255 - d : d - 255);
    sums[d] /= (float)cnt;
  }
  __syncthreads();
  float4* Ob = (float4*)(Spnew + (size_t)b * NRR);
  for (int i4 = t; i4 < NRR / 4; i4 += 256) {
    int r = i4 >> 6, c = (i4 & 63) * 4;
    float4 tv = Tb[i4], sv = Spb[i4];
    int d = c - r + 255;
    float4 o;
    o.x = sv.x - tv.x + sums[d + 0];
    o.y = sv.y - tv.y + sums[d + 1];
    o.z = sv.z - tv.z + sums[d + 2];
    o.w = sv.w - tv.w + sums[d + 3];
    Ob[i4] = o;
  }
}

// ---------------------------------------------------------------------------
extern "C" void kernel_launch(void* const* d_in, const int* in_sizes, int n_in,
                              void* d_out, int out_size, void* d_ws, size_t ws_size,
                              hipStream_t stream) {
  const float* T  = (const float*)d_in[0];
  const float* Tp = (const float*)d_in[1];
  const float* Sp = (const float*)d_in[2];
  const float* w1 = (const float*)d_in[3];
  const float* w2 = (const float*)d_in[4];
  const float* w3 = (const float*)d_in[5];
  const float* w4 = (const float*)d_in[6];
  const int*   Kp = (const int*)d_in[7];
  float* out = (float*)d_out;

  float* slot0 = out;                   // G, then T
  float* slot1 = out + BRR;             // A, then Tpnew
  float* slot2 = out + 2 * (size_t)BRR; // Q/Z + small buffers, then Spnew
  float* G = slot0;
  float* A = slot1;
  float* Qb[2] = { slot2, slot2 + BNL };
  float* sc    = slot2 + 2 * (size_t)BNL;
  float* Mbuf  = sc;
  float* Vbuf  = sc + 524288;
  float* Ubuf  = sc + 2 * 524288;
  float* Cbuf  = sc + 3 * 524288;
  int*   topidx = (int*)(sc + 4 * 524288);

  k_build_A<<<BRR / 4 / 256, 256, 0, stream>>>(T, Tp, Sp, w1, w2, w3, w4, A);
  k_aat<<<dim3(4, 4, B_), 256, 0, stream>>>(A, G);
  k_init_Y<<<BNL / 256, 256, 0, stream>>>(Qb[0]);
  k_qr<<<B_, 256, 0, stream>>>(Qb[0]);

  int cur = 0;
  for (int it = 0; it < 16; ++it) {
    k_gq<<<dim3(4, B_), 256, 0, stream>>>(G, Qb[cur], Qb[1 - cur]);
    cur = 1 - cur;
    if ((it & 3) == 3) k_qr<<<B_, 256, 0, stream>>>(Qb[cur]);  // it 3,7,11,15
  }
  // Rayleigh-Ritz: Z = G*Q, M = Q^T Z
  k_gq<<<dim3(4, B_), 256, 0, stream>>>(G, Qb[cur], Qb[1 - cur]);
  k_xty<<<B_, 256, 0, stream>>>(Qb[cur], Qb[1 - cur], Mbuf);
  k_jacobi<<<B_, 256, 0, stream>>>(Mbuf, Vbuf);
  k_topk<<<B_, 64, 0, stream>>>(Mbuf, Kp, topidx);
  k_formU<<<B_, 256, 0, stream>>>(Qb[cur], Vbuf, topidx, Kp, Ubuf);
  k_utA<<<B_, 256, 0, stream>>>(Ubuf, A, Kp, Cbuf);
  k_uc<<<dim3(16, B_), 256, 0, stream>>>(Ubuf, Cbuf, Kp, slot1);  // overwrites A
  k_copyT<<<BRR / 4 / 256, 256, 0, stream>>>(T, slot0);           // overwrites G
  k_spnew<<<B_, 256, 0, stream>>>(Sp, slot1, slot2);              // overwrites scratch
}

// Round 4
// 1542.413 us; speedup vs baseline: 3.7252x; 1.1350x over previous
//
#include <hip/hip_runtime.h>
#include <math.h>

#define B_   128
#define N_   256
#define L_   64
#define NRR  (N_*N_)          // 65536
#define BRR  (B_*NRR)         // 8388608
#define BNL  (B_*N_*L_)       // 2097152

static __device__ __forceinline__ void fma4(float4& a, float s, const float4& v) {
  a.x += s * v.x; a.y += s * v.y; a.z += s * v.z; a.w += s * v.w;
}

// ---------------------------------------------------------------------------
// A = diag(w1)*Sp + diag(w2)*Tp + w4.*Tp + w3.*T
// ---------------------------------------------------------------------------
__global__ __launch_bounds__(256) void k_build_A(
    const float* __restrict__ T, const float* __restrict__ Tp,
    const float* __restrict__ Sp, const float* __restrict__ w1,
    const float* __restrict__ w2, const float* __restrict__ w3,
    const float* __restrict__ w4, float* __restrict__ A) {
  int i4 = blockIdx.x * 256 + threadIdx.x;
  if (i4 >= BRR / 4) return;
  int rc4 = i4 & (NRR / 4 - 1);
  int r = rc4 >> 6;
  float a1 = w1[r * N_ + r], a2 = w2[r * N_ + r];
  float4 sp = ((const float4*)Sp)[i4];
  float4 tp = ((const float4*)Tp)[i4];
  float4 tt = ((const float4*)T)[i4];
  float4 w3v = ((const float4*)w3)[rc4];
  float4 w4v = ((const float4*)w4)[rc4];
  float4 o;
  o.x = a1 * sp.x + a2 * tp.x + w4v.x * tp.x + w3v.x * tt.x;
  o.y = a1 * sp.y + a2 * tp.y + w4v.y * tp.y + w3v.y * tt.y;
  o.z = a1 * sp.z + a2 * tp.z + w4v.z * tp.z + w3v.z * tt.z;
  o.w = a1 * sp.w + a2 * tp.w + w4v.w * tp.w + w3v.w * tt.w;
  ((float4*)A)[i4] = o;
}

// ---------------------------------------------------------------------------
// G = A * A^T  (batched), 64x64 tile, symmetric mirror
// ---------------------------------------------------------------------------
__global__ __launch_bounds__(256) void k_aat(const float* __restrict__ A,
                                             float* __restrict__ G) {
  int b = blockIdx.z, ti = blockIdx.x, tj = blockIdx.y;
  if (ti > tj) return;
  int it = ti * 64, jt = tj * 64;
  __shared__ __align__(16) float AsT[32][68];
  __shared__ __align__(16) float BsT[32][68];
  const float* Ab = A + (size_t)b * NRR;
  int t = threadIdx.x, tx = t & 15, ty = t >> 4;
  float4 acc[4] = {};
  int kk = t & 31, r0 = t >> 5;
  for (int k0 = 0; k0 < N_; k0 += 32) {
#pragma unroll
    for (int p = 0; p < 8; ++p) {
      int r = r0 + p * 8;
      AsT[kk][r] = Ab[(it + r) * N_ + k0 + kk];
      BsT[kk][r] = Ab[(jt + r) * N_ + k0 + kk];
    }
    __syncthreads();
#pragma unroll
    for (int k = 0; k < 32; ++k) {
      float4 av = *(const float4*)&AsT[k][ty * 4];
      float4 bv = *(const float4*)&BsT[k][tx * 4];
      fma4(acc[0], av.x, bv);
      fma4(acc[1], av.y, bv);
      fma4(acc[2], av.z, bv);
      fma4(acc[3], av.w, bv);
    }
    __syncthreads();
  }
  float* Gb = G + (size_t)b * NRR;
#pragma unroll
  for (int i = 0; i < 4; ++i)
    *(float4*)&Gb[(it + ty * 4 + i) * N_ + jt + tx * 4] = acc[i];
  if (ti < tj) {
    const float* a = (const float*)acc;
#pragma unroll
    for (int i = 0; i < 4; ++i)
#pragma unroll
      for (int j = 0; j < 4; ++j)
        Gb[(jt + tx * 4 + j) * N_ + it + ty * 4 + i] = a[i * 4 + j];
  }
}

// ---------------------------------------------------------------------------
// Y = G * Q. G streamed DIRECT FROM GLOBAL (L2/L3-hot, lane-broadcast rows),
// Q staged in LDS. 64x64 tile, 128 threads, 8x4 acc per thread.
// ---------------------------------------------------------------------------
__global__ __launch_bounds__(128) void k_gq(const float* __restrict__ G,
                                            const float* __restrict__ Q,
                                            float* __restrict__ Y) {
  __shared__ __align__(16) float Qs[64][68];
  int b = blockIdx.y, it = blockIdx.x * 64;
  const float* Gb = G + (size_t)b * NRR;
  const float* Qb = Q + (size_t)b * (N_ * L_);
  int t = threadIdx.x, cx = t & 15, ry = t >> 4;
  const float* gr[8];
#pragma unroll
  for (int i = 0; i < 8; ++i) gr[i] = Gb + (size_t)(it + ry * 8 + i) * N_;
  float4 acc[8] = {};
  for (int kc = 0; kc < N_; kc += 64) {
#pragma unroll
    for (int p = 0; p < 8; ++p) {
      int idx = t + p * 128;
      int r = idx >> 4, c4 = idx & 15;
      *(float4*)&Qs[r][c4 * 4] = *(const float4*)&Qb[(kc + r) * L_ + c4 * 4];
    }
    __syncthreads();
#pragma unroll 4
    for (int k4 = 0; k4 < 16; ++k4) {
      int k = k4 * 4;
      float4 g[8];
#pragma unroll
      for (int i = 0; i < 8; ++i) g[i] = *(const float4*)&gr[i][kc + k];
      float4 q0 = *(const float4*)&Qs[k + 0][cx * 4];
      float4 q1 = *(const float4*)&Qs[k + 1][cx * 4];
      float4 q2 = *(const float4*)&Qs[k + 2][cx * 4];
      float4 q3 = *(const float4*)&Qs[k + 3][cx * 4];
#pragma unroll
      for (int i = 0; i < 8; ++i) {
        fma4(acc[i], g[i].x, q0);
        fma4(acc[i], g[i].y, q1);
        fma4(acc[i], g[i].z, q2);
        fma4(acc[i], g[i].w, q3);
      }
    }
    __syncthreads();
  }
  float* Yb = Y + (size_t)b * (N_ * L_);
#pragma unroll
  for (int i = 0; i < 8; ++i)
    *(float4*)&Yb[(it + ry * 8 + i) * L_ + cx * 4] = acc[i];
}

// ---------------------------------------------------------------------------
// M = X^T * Y  (256x64 -> 64x64), global-direct streaming, no LDS.
// ---------------------------------------------------------------------------
__global__ __launch_bounds__(256) void k_xty(const float* __restrict__ X,
                                             const float* __restrict__ Y,
                                             float* __restrict__ Mo) {
  int b = blockIdx.x, t = threadIdx.x, tx = t & 15, ty = t >> 4;
  const float* Xb = X + (size_t)b * (N_ * L_);
  const float* Yb = Y + (size_t)b * (N_ * L_);
  float4 a0 = {}, a1 = {}, a2 = {}, a3 = {};
#pragma unroll 4
  for (int k = 0; k < N_; ++k) {
    float4 xv = *(const float4*)&Xb[k * L_ + ty * 4];
    float4 yv = *(const float4*)&Yb[k * L_ + tx * 4];
    fma4(a0, xv.x, yv); fma4(a1, xv.y, yv);
    fma4(a2, xv.z, yv); fma4(a3, xv.w, yv);
  }
  float* Mb = Mo + (size_t)b * L_ * L_;
  *(float4*)&Mb[(ty * 4 + 0) * L_ + tx * 4] = a0;
  *(float4*)&Mb[(ty * 4 + 1) * L_ + tx * 4] = a1;
  *(float4*)&Mb[(ty * 4 + 2) * L_ + tx * 4] = a2;
  *(float4*)&Mb[(ty * 4 + 3) * L_ + tx * 4] = a3;
}

// ---------------------------------------------------------------------------
// deterministic pseudo-random init for Y0
// ---------------------------------------------------------------------------
__global__ __launch_bounds__(256) void k_init_Y(float* __restrict__ Y) {
  int idx = blockIdx.x * 256 + threadIdx.x;
  if (idx >= BNL) return;
  unsigned u = (unsigned)idx * 2654435761u;
  u ^= u >> 16; u *= 2246822519u; u ^= u >> 13; u *= 3266489917u; u ^= u >> 16;
  Y[idx] = (float)(int)u * 4.6566129e-10f;
}

// ---------------------------------------------------------------------------
// Fused CholQR v2: Gram global-direct, BLOCKED Cholesky (8x8, 24 barriers),
// register TRSM. One 256-thread block per batch.
// ---------------------------------------------------------------------------
__global__ __launch_bounds__(256) void k_qr(float* __restrict__ Q) {
  __shared__ __align__(16) float S[64][68];
  __shared__ float dinv[64];
  int b = blockIdx.x, t = threadIdx.x, tx = t & 15, ty = t >> 4;
  float* Qb = Q + (size_t)b * (N_ * L_);
  // Gram: S = P^T P, streaming P from global (L2-hot)
  {
    float4 a0 = {}, a1 = {}, a2 = {}, a3 = {};
#pragma unroll 4
    for (int k = 0; k < N_; ++k) {
      float4 xv = *(const float4*)&Qb[k * L_ + ty * 4];
      float4 yv = *(const float4*)&Qb[k * L_ + tx * 4];
      fma4(a0, xv.x, yv); fma4(a1, xv.y, yv);
      fma4(a2, xv.z, yv); fma4(a3, xv.w, yv);
    }
    *(float4*)&S[ty * 4 + 0][tx * 4] = a0;
    *(float4*)&S[ty * 4 + 1][tx * 4] = a1;
    *(float4*)&S[ty * 4 + 2][tx * 4] = a2;
    *(float4*)&S[ty * 4 + 3][tx * 4] = a3;
  }
  __syncthreads();
  // blocked Cholesky, block size 8
  for (int kb = 0; kb < 8; ++kb) {
    int base = kb * 8;
    if (t == 0) {
      for (int q = 0; q < 8; ++q) {
        float d = S[base + q][base + q];
        for (int w = 0; w < q; ++w) d -= S[base + q][base + w] * S[base + q][base + w];
        d = sqrtf(fmaxf(d, 1e-20f));
        S[base + q][base + q] = d;
        float di = 1.f / d;
        dinv[base + q] = di;
        for (int r = q + 1; r < 8; ++r) {
          float v = S[base + r][base + q];
          for (int w = 0; w < q; ++w) v -= S[base + r][base + w] * S[base + q][base + w];
          S[base + r][base + q] = v * di;
        }
      }
    }
    __syncthreads();
    int nrows = 56 - base;
    if (t < nrows) {        // panel TRSM, thread per row
      int i = base + 8 + t;
      float x[8];
#pragma unroll
      for (int q = 0; q < 8; ++q) {
        float v = S[i][base + q];
        for (int w = 0; w < q; ++w) v -= S[base + q][base + w] * x[w];
        x[q] = v * dinv[base + q];
      }
#pragma unroll
      for (int q = 0; q < 8; ++q) S[i][base + q] = x[q];
    }
    __syncthreads();
    if (nrows > 0) {        // rank-8 trailing update (full square, stays symm)
      for (int e = t; e < nrows * 64; e += 256) {
        int io = e >> 6, ko = e & 63;
        if (ko < nrows) {
          int i = base + 8 + io, k = base + 8 + ko;
          float4 p0 = *(const float4*)&S[i][base], p1 = *(const float4*)&S[i][base + 4];
          float4 r0 = *(const float4*)&S[k][base], r1 = *(const float4*)&S[k][base + 4];
          S[i][k] -= p0.x * r0.x + p0.y * r0.y + p0.z * r0.z + p0.w * r0.w
                   + p1.x * r1.x + p1.y * r1.y + p1.z * r1.z + p1.w * r1.w;
        }
      }
    }
    __syncthreads();
  }
  // TRSM: row t of panel (from global), solve vs L^T, write back
  {
    float x[64];
#pragma unroll
    for (int u = 0; u < 16; ++u) {
      float4 v = *(const float4*)&Qb[t * L_ + u * 4];
      x[u * 4 + 0] = v.x; x[u * 4 + 1] = v.y;
      x[u * 4 + 2] = v.z; x[u * 4 + 3] = v.w;
    }
#pragma unroll
    for (int j = 0; j < 64; ++j) {
      float s = x[j];
#pragma unroll
      for (int mq = 0; mq < (j >> 2); ++mq) {
        float4 lv = *(const float4*)&S[j][mq * 4];
        s -= lv.x * x[mq * 4 + 0] + lv.y * x[mq * 4 + 1]
           + lv.z * x[mq * 4 + 2] + lv.w * x[mq * 4 + 3];
      }
#pragma unroll
      for (int k = (j & ~3); k < j; ++k) s -= S[j][k] * x[k];
      x[j] = s * dinv[j];
    }
#pragma unroll
    for (int u = 0; u < 16; ++u) {
      float4 v;
      v.x = x[u * 4 + 0]; v.y = x[u * 4 + 1];
      v.z = x[u * 4 + 2]; v.w = x[u * 4 + 3];
      *(float4*)&Qb[t * L_ + u * 4] = v;
    }
  }
}

// ---------------------------------------------------------------------------
// parallel cyclic Jacobi: 256 thr, per-thread param compute (no wave-0 phase),
// 2 barriers/round, 4 sweeps. Safety: each pair's sensitive triple
// (i,i),(i,j),(j,j) is only written by its own 8-lane group (one wave);
// lockstep orders the group's param reads before its row writes.
// ---------------------------------------------------------------------------
__global__ __launch_bounds__(256) void k_jacobi(float* __restrict__ Mg,
                                                float* __restrict__ Vg) {
  __shared__ __align__(16) float A[64][68];
  __shared__ __align__(16) float Vt[64][68];
  int b = blockIdx.x, t = threadIdx.x;
  float* Mb = Mg + (size_t)b * L_ * L_;
#pragma unroll
  for (int p = 0; p < 16; ++p) {
    int e = t + p * 256, r = e >> 6, c = e & 63;
    A[r][c] = Mb[r * L_ + c];
    Vt[r][c] = (r == c) ? 1.f : 0.f;
  }
  __syncthreads();
  int m = t >> 3, u = t & 7;
  for (int sweep = 0; sweep < 4; ++sweep) {
    for (int rnd = 0; rnd < 63; ++rnd) {
      int i, j;
      if (m == 0) { i = rnd; j = 63; }
      else {
        int a = rnd + m;       if (a >= 63) a -= 63;
        int bb = rnd + 63 - m; if (bb >= 63) bb -= 63;
        i = min(a, bb); j = max(a, bb);
      }
      // per-thread rotation params
      float aii = A[i][i], ajj = A[j][j], aij = A[i][j];
      float c_ = 1.f, s_ = 0.f;
      if (fabsf(aij) > 1e-12f) {
        float tau = (ajj - aii) / (2.f * aij);
        float tt = (tau >= 0.f ? 1.f : -1.f) / (fabsf(tau) + sqrtf(1.f + tau * tau));
        c_ = rsqrtf(1.f + tt * tt);
        s_ = tt * c_;
      }
      // row phase: A <- J^T A ; Vt <- J^T Vt  (cols 8u..8u+7)
      {
        float4* Ai = (float4*)&A[i][u * 8];
        float4* Aj = (float4*)&A[j][u * 8];
        float4* Vi = (float4*)&Vt[i][u * 8];
        float4* Vj = (float4*)&Vt[j][u * 8];
#pragma unroll
        for (int q = 0; q < 2; ++q) {
          float4 x = Ai[q], y = Aj[q], nx, ny;
          nx.x = c_ * x.x - s_ * y.x; ny.x = s_ * x.x + c_ * y.x;
          nx.y = c_ * x.y - s_ * y.y; ny.y = s_ * x.y + c_ * y.y;
          nx.z = c_ * x.z - s_ * y.z; ny.z = s_ * x.z + c_ * y.z;
          nx.w = c_ * x.w - s_ * y.w; ny.w = s_ * x.w + c_ * y.w;
          Ai[q] = nx; Aj[q] = ny;
          float4 vx = Vi[q], vy = Vj[q], mx, my;
          mx.x = c_ * vx.x - s_ * vy.x; my.x = s_ * vx.x + c_ * vy.x;
          mx.y = c_ * vx.y - s_ * vy.y; my.y = s_ * vx.y + c_ * vy.y;
          mx.z = c_ * vx.z - s_ * vy.z; my.z = s_ * vx.z + c_ * vy.z;
          mx.w = c_ * vx.w - s_ * vy.w; my.w = s_ * vx.w + c_ * vy.w;
          Vi[q] = mx; Vj[q] = my;
        }
      }
      __syncthreads();
      // col phase: A <- A J  (rows u, u+8, ..., u+56)
#pragma unroll
      for (int p = 0; p < 8; ++p) {
        int k = u + 8 * p;
        float x = A[k][i], y = A[k][j];
        A[k][i] = c_ * x - s_ * y;
        A[k][j] = s_ * x + c_ * y;
      }
      __syncthreads();
    }
  }
  if (t < 64) Mb[t * L_ + t] = A[t][t];
  float* Vb = Vg + (size_t)b * L_ * L_;
#pragma unroll
  for (int p = 0; p < 16; ++p) {
    int e = t + p * 256, r = e >> 6, c = e & 63;
    Vb[r * L_ + c] = Vt[r][c];
  }
}

// ---------------------------------------------------------------------------
// pick indices of K largest eigenvalues (diag of M)
// ---------------------------------------------------------------------------
__global__ void k_topk(const float* __restrict__ Mg, const int* __restrict__ Kp,
                       int* __restrict__ topidx) {
  int b = blockIdx.x;
  if (threadIdx.x != 0) return;
  const float* Mb = Mg + (size_t)b * L_ * L_;
  int K = *Kp; if (K > 16) K = 16;
  float vals[64]; bool used[64];
  for (int i = 0; i < 64; ++i) { vals[i] = Mb[i * L_ + i]; used[i] = false; }
  for (int j = 0; j < K; ++j) {
    int best = 0; float bv = -1e30f;
    for (int i = 0; i < 64; ++i)
      if (!used[i] && vals[i] > bv) { bv = vals[i]; best = i; }
    used[best] = true;
    topidx[b * 16 + j] = best;
  }
}

// ---------------------------------------------------------------------------
// U = Q * V[:, topidx]   (V passed transposed: Vt rows are eigenvectors)
// ---------------------------------------------------------------------------
__global__ __launch_bounds__(256) void k_formU(const float* __restrict__ Q,
                                               const float* __restrict__ Vtg,
                                               const int* __restrict__ topidx,
                                               const int* __restrict__ Kp,
                                               float* __restrict__ U) {
  __shared__ float Vs[64][17];
  int b = blockIdx.x, t = threadIdx.x;
  int K = *Kp; if (K > 16) K = 16;
  if (t < 64) {
    for (int j = 0; j < 16; ++j)
      Vs[t][j] = (j < K)
        ? Vtg[(size_t)b * L_ * L_ + (size_t)topidx[b * 16 + j] * L_ + t]
        : 0.f;
  }
  __syncthreads();
  const float* Qb = Q + (size_t)b * N_ * L_;
  float qv[64];
#pragma unroll
  for (int k = 0; k < 64; ++k) qv[k] = Qb[t * L_ + k];
  float* Ub = U + (size_t)b * N_ * 16;
  for (int j = 0; j < 16; ++j) {
    float s = 0.f;
    if (j < K) {
#pragma unroll
      for (int k = 0; k < 64; ++k) s += qv[k] * Vs[k][j];
    }
    Ub[t * 16 + j] = s;
  }
}

// ---------------------------------------------------------------------------
// C = U^T * A   (Kx256)
// ---------------------------------------------------------------------------
__global__ __launch_bounds__(256) void k_utA(const float* __restrict__ U,
                                             const float* __restrict__ A,
                                             const int* __restrict__ Kp,
                                             float* __restrict__ C) {
  __shared__ float Us[256][17];
  int b = blockIdx.x, t = threadIdx.x;
  int K = *Kp; if (K > 16) K = 16;
  const float* Ub = U + (size_t)b * N_ * 16;
  for (int p = 0; p < 16; ++p) {
    int r = (t >> 4) + p * 16, j = t & 15;
    Us[r][j] = Ub[r * 16 + j];
  }
  __syncthreads();
  const float* Ab = A + (size_t)b * NRR;
  float acc[16];
  for (int j = 0; j < 16; ++j) acc[j] = 0.f;
  for (int i = 0; i < N_; ++i) {
    float av = Ab[i * N_ + t];
    for (int j = 0; j < K; ++j) acc[j] += Us[i][j] * av;
  }
  float* Cb = C + (size_t)b * 16 * N_;
  for (int j = 0; j < 16; ++j) Cb[j * N_ + t] = (j < K) ? acc[j] : 0.f;
}

// ---------------------------------------------------------------------------
// Tpnew = U * C   (rank-K), 16 rows per block
// ---------------------------------------------------------------------------
__global__ __launch_bounds__(256) void k_uc(const float* __restrict__ U,
                                            const float* __restrict__ C,
                                            const int* __restrict__ Kp,
                                            float* __restrict__ Tpnew) {
  __shared__ float Cs[16][256];
  __shared__ float Us[16][17];
  int b = blockIdx.y, rt = blockIdx.x * 16, t = threadIdx.x;
  int K = *Kp; if (K > 16) K = 16;
  const float* Cb = C + (size_t)b * 16 * N_;
  for (int j = 0; j < 16; ++j) Cs[j][t] = Cb[j * N_ + t];
  Us[t >> 4][t & 15] = U[(size_t)b * N_ * 16 + (size_t)(rt + (t >> 4)) * 16 + (t & 15)];
  __syncthreads();
  float* Ob = Tpnew + (size_t)b * NRR;
  for (int r = 0; r < 16; ++r) {
    float s = 0.f;
    for (int j = 0; j < K; ++j) s += Us[r][j] * Cs[j][t];
    Ob[(rt + r) * N_ + t] = s;
  }
}

// ---------------------------------------------------------------------------
// copy T to out slot 0
// ---------------------------------------------------------------------------
__global__ __launch_bounds__(256) void k_copyT(const float* __restrict__ T,
                                               float* __restrict__ O) {
  int i4 = blockIdx.x * 256 + threadIdx.x;
  if (i4 < BRR / 4) ((float4*)O)[i4] = ((const float4*)T)[i4];
}

// ---------------------------------------------------------------------------
// Spnew = Sp - Tpnew + averaging_diagonals(2*Tpnew - Sp). One block/batch.
// ---------------------------------------------------------------------------
__global__ __launch_bounds__(256) void k_spnew(const float* __restrict__ Sp,
                                               const float* __restrict__ Tpnew,
                                               float* __restrict__ Spnew) {
  __shared__ float sums[512];
  int b = blockIdx.x, t = threadIdx.x;
  for (int i = t; i < 512; i += 256) sums[i] = 0.f;
  __syncthreads();
  const float4* Spb = (const float4*)(Sp + (size_t)b * NRR);
  const float4* Tb  = (const float4*)(Tpnew + (size_t)b * NRR);
  for (int i4 = t; i4 < NRR / 4; i4 += 256) {
    int r = i4 >> 6, c = (i4 & 63) * 4;
    float4 tv = Tb[i4], sv = Spb[i4];
    int d = c - r + 255;
    atomicAdd(&sums[d + 0], 2.f * tv.x - sv.x);
    atomicAdd(&sums[d + 1], 2.f * tv.y - sv.y);
    atomicAdd(&sums[d + 2], 2.f * tv.z - sv.z);
    atomicAdd(&sums[d + 3], 2.f * tv.w - sv.w);
  }
  __syncthreads();
  for (int d = t; d < 511; d += 256) {
    int cnt = 256 - (d < 255 ? 255 - d : d - 255);
    sums[d] /= (float)cnt;
  }
  __syncthreads();
  float4* Ob = (float4*)(Spnew + (size_t)b * NRR);
  for (int i4 = t; i4 < NRR / 4; i4 += 256) {
    int r = i4 >> 6, c = (i4 & 63) * 4;
    float4 tv = Tb[i4], sv = Spb[i4];
    int d = c - r + 255;
    float4 o;
    o.x = sv.x - tv.x + sums[d + 0];
    o.y = sv.y - tv.y + sums[d + 1];
    o.z = sv.z - tv.z + sums[d + 2];
    o.w = sv.w - tv.w + sums[d + 3];
    Ob[i4] = o;
  }
}

// ---------------------------------------------------------------------------
extern "C" void kernel_launch(void* const* d_in, const int* in_sizes, int n_in,
                              void* d_out, int out_size, void* d_ws, size_t ws_size,
                              hipStream_t stream) {
  const float* T  = (const float*)d_in[0];
  const float* Tp = (const float*)d_in[1];
  const float* Sp = (const float*)d_in[2];
  const float* w1 = (const float*)d_in[3];
  const float* w2 = (const float*)d_in[4];
  const float* w3 = (const float*)d_in[5];
  const float* w4 = (const float*)d_in[6];
  const int*   Kp = (const int*)d_in[7];
  float* out = (float*)d_out;

  float* slot0 = out;                   // G, then T
  float* slot1 = out + BRR;             // A, then Tpnew
  float* slot2 = out + 2 * (size_t)BRR; // Q/Z + small buffers, then Spnew
  float* G = slot0;
  float* A = slot1;
  float* Qb[2] = { slot2, slot2 + BNL };
  float* sc    = slot2 + 2 * (size_t)BNL;
  float* Mbuf  = sc;
  float* Vbuf  = sc + 524288;
  float* Ubuf  = sc + 2 * 524288;
  float* Cbuf  = sc + 3 * 524288;
  int*   topidx = (int*)(sc + 4 * 524288);

  k_build_A<<<BRR / 4 / 256, 256, 0, stream>>>(T, Tp, Sp, w1, w2, w3, w4, A);
  k_aat<<<dim3(4, 4, B_), 256, 0, stream>>>(A, G);
  k_init_Y<<<BNL / 256, 256, 0, stream>>>(Qb[0]);
  k_qr<<<B_, 256, 0, stream>>>(Qb[0]);

  int cur = 0;
  for (int it = 0; it < 12; ++it) {
    k_gq<<<dim3(4, B_), 128, 0, stream>>>(G, Qb[cur], Qb[1 - cur]);
    cur = 1 - cur;
    if ((it & 3) == 3) k_qr<<<B_, 256, 0, stream>>>(Qb[cur]);  // it 3,7,11
  }
  // Rayleigh-Ritz: Z = G*Q, M = Q^T Z
  k_gq<<<dim3(4, B_), 128, 0, stream>>>(G, Qb[cur], Qb[1 - cur]);
  k_xty<<<B_, 256, 0, stream>>>(Qb[cur], Qb[1 - cur], Mbuf);
  k_jacobi<<<B_, 256, 0, stream>>>(Mbuf, Vbuf);
  k_topk<<<B_, 64, 0, stream>>>(Mbuf, Kp, topidx);
  k_formU<<<B_, 256, 0, stream>>>(Qb[cur], Vbuf, topidx, Kp, Ubuf);
  k_utA<<<B_, 256, 0, stream>>>(Ubuf, A, Kp, Cbuf);
  k_uc<<<dim3(16, B_), 256, 0, stream>>>(Ubuf, Cbuf, Kp, slot1);  // overwrites A
  k_copyT<<<BRR / 4 / 256, 256, 0, stream>>>(T, slot0);           // overwrites G
  k_spnew<<<B_, 256, 0, stream>>>(Sp, slot1, slot2);              // overwrites scratch
}